// Round 9
// baseline (341.958 us; speedup 1.0000x reference)
//
#include <hip/hip_runtime.h>
#include <cstdint>
#include <cstddef>

#define B_  2
#define H_  8
#define C_  2048
#define HW_ 64
#define HD_ 512   // H_*HW_
#define N1_ 2097152  // B_*H_*C_*HW_

typedef __attribute__((ext_vector_type(8))) short short8;
typedef __attribute__((ext_vector_type(4))) short short4v;
typedef __attribute__((ext_vector_type(4))) float f32x4;
typedef __attribute__((ext_vector_type(4))) int   int4v;
typedef unsigned short us;

static __device__ inline us f2bf(float f) {           // RNE
    unsigned u = __builtin_bit_cast(unsigned, f);
    u = u + 0x7FFFu + ((u >> 16) & 1u);
    return (us)(u >> 16);
}
static __device__ inline us f2bf_t(float f) {         // truncate (hot path)
    return (us)(__builtin_bit_cast(unsigned, f) >> 16);
}
static __device__ inline float bf2f(us s) {
    unsigned u = ((unsigned)s) << 16;
    return __builtin_bit_cast(float, u);
}
static __device__ inline f32x4 mfma16(short8 a, short8 b, f32x4 c) {
    return __builtin_amdgcn_mfma_f32_16x16x32_bf16(a, b, c, 0, 0, 0);
}
static __device__ inline short8 negbf(short8 v) {
    int4v u = __builtin_bit_cast(int4v, v);
    u ^= (int)0x80008000;
    return __builtin_bit_cast(short8, u);
}
// b64-pair LDS fragment load (rows padded -> 8B-aligned only)
static __device__ inline short8 lds_frag(const us* p) {
    short4v a = *(const short4v*)p;
    short4v b = *(const short4v*)(p + 4);
    return __builtin_shufflevector(a, b, 0, 1, 2, 3, 4, 5, 6, 7);
}
// V fragment read for permuted PV contraction (R16-verified): 8B at +0, +16
static __device__ inline short8 lds_fragg(const us* p) {
    short4v a = *(const short4v*)p;
    short4v b = *(const short4v*)(p + 16);
    return __builtin_shufflevector(a, b, 0, 1, 2, 3, 4, 5, 6, 7);
}
// pack two f32 into bf16x2 high word + bf16x2 residual word (R16-verified)
static __device__ inline void pkhl(float a, float b, unsigned &hw, unsigned &lw) {
    us ha = f2bf_t(a), hb = f2bf_t(b);
    hw = (unsigned)ha | ((unsigned)hb << 16);
    float la = a - bf2f(ha), lb = b - bf2f(hb);
    lw = (unsigned)f2bf_t(la) | ((unsigned)f2bf_t(lb) << 16);
}
static __device__ inline short8 bcs8(unsigned a, unsigned b, unsigned c, unsigned d) {
    int4v v = {(int)a, (int)b, (int)c, (int)d};
    return __builtin_bit_cast(short8, v);
}

// ---------------- Projection + rotary phase ----------------
__global__ __launch_bounds__(256) void proj_kernel(
    const float* __restrict__ x, const float* __restrict__ WQ,
    const float* __restrict__ WK, const float* __restrict__ WV,
    const float* __restrict__ theta,
    us* __restrict__ Qch, us* __restrict__ Qcl,
    us* __restrict__ K1h, us* __restrict__ K1l,
    us* __restrict__ VTh, us* __restrict__ VTl)
{
    __shared__ float smem[3 * 64 * 68 + 32 * 68];   // 60,928 B
    float* sWT = smem;               // [3][64 j][68 i]
    float* sx  = smem + 3 * 64 * 68; // [32 c][68 i]
    int tid = threadIdx.x;
    int bh = blockIdx.y; int h = bh & 7;
    int c0 = blockIdx.x * 32;
    for (int t = tid; t < 1024; t += 256) {
        int j4 = (t & 15) * 4, i = t >> 4;
        float4 wq = *(const float4*)&WQ[(h * 64 + i) * 64 + j4];
        float4 wk = *(const float4*)&WK[(h * 64 + i) * 64 + j4];
        float4 wv = *(const float4*)&WV[(h * 64 + i) * 64 + j4];
        sWT[(j4 + 0) * 68 + i] = wq.x; sWT[(j4 + 1) * 68 + i] = wq.y;
        sWT[(j4 + 2) * 68 + i] = wq.z; sWT[(j4 + 3) * 68 + i] = wq.w;
        sWT[64 * 68 + (j4 + 0) * 68 + i] = wk.x; sWT[64 * 68 + (j4 + 1) * 68 + i] = wk.y;
        sWT[64 * 68 + (j4 + 2) * 68 + i] = wk.z; sWT[64 * 68 + (j4 + 3) * 68 + i] = wk.w;
        sWT[2 * 64 * 68 + (j4 + 0) * 68 + i] = wv.x; sWT[2 * 64 * 68 + (j4 + 1) * 68 + i] = wv.y;
        sWT[2 * 64 * 68 + (j4 + 2) * 68 + i] = wv.z; sWT[2 * 64 * 68 + (j4 + 3) * 68 + i] = wv.w;
    }
    for (int t = tid; t < 512; t += 256) {
        int i4 = (t & 15) * 4, c = t >> 4;
        *(float4*)&sx[c * 68 + i4] =
            *(const float4*)&x[((size_t)((bh >> 3) * C_ + c0 + c)) * HD_ + h * 64 + i4];
    }
    __syncthreads();
    int j = tid & 63, cg = tid >> 6;     // cg uniform per wave
    float aq[8] = {}, ak[8] = {}, av[8] = {};
    const float* pw0 = &sWT[j * 68];
    const float* pw1 = &sWT[64 * 68 + j * 68];
    const float* pw2 = &sWT[2 * 64 * 68 + j * 68];
    const float* px  = &sx[cg * 8 * 68];
    #pragma unroll 2
    for (int i0 = 0; i0 < 64; i0 += 4) {
        float4 w0 = *(const float4*)(pw0 + i0);
        float4 w1 = *(const float4*)(pw1 + i0);
        float4 w2 = *(const float4*)(pw2 + i0);
        #pragma unroll
        for (int cc = 0; cc < 8; ++cc) {
            float4 xv = *(const float4*)(px + cc * 68 + i0);
            aq[cc] += xv.x * w0.x + xv.y * w0.y + xv.z * w0.z + xv.w * w0.w;
            ak[cc] += xv.x * w1.x + xv.y * w1.y + xv.z * w1.z + xv.w * w1.w;
            av[cc] += xv.x * w2.x + xv.y * w2.y + xv.z * w2.z + xv.w * w2.w;
        }
    }
    float th = theta[h * 64 + j];
    #pragma unroll
    for (int cc = 0; cc < 8; ++cc) {
        int c = c0 + cg * 8 + cc;
        float sn, cs;
        sincosf((float)c * th, &sn, &cs);
        float qr = aq[cc] * cs, qi = aq[cc] * sn;
        float kr = ak[cc] * cs, nki = ak[cc] * sn;   // nki = -Ki
        size_t rq = ((size_t)bh * C_ + c) * 128;
        us h0;
        h0 = f2bf(qr);  Qch[rq + j]      = h0; Qcl[rq + j]      = f2bf(qr  - bf2f(h0));
        h0 = f2bf(qi);  Qch[rq + 64 + j] = h0; Qcl[rq + 64 + j] = f2bf(qi  - bf2f(h0));
        h0 = f2bf(kr);  K1h[rq + j]      = h0; K1l[rq + j]      = f2bf(kr  - bf2f(h0));
        h0 = f2bf(nki); K1h[rq + 64 + j] = h0; K1l[rq + 64 + j] = f2bf(nki - bf2f(h0));
    }
    __syncthreads();
    float* T0 = smem;                   // [64][33]
    #pragma unroll
    for (int cc = 0; cc < 8; ++cc)
        T0[j * 33 + cg * 8 + cc] = av[cc];
    __syncthreads();
    int cc2 = tid & 31, jg = tid >> 5;
    #pragma unroll
    for (int jj = 0; jj < 8; ++jj) {
        int jr = jg * 8 + jj;
        float v = T0[jr * 33 + cc2];
        us hh = f2bf(v);
        size_t o = ((size_t)bh * 64 + jr) * C_ + c0 + cc2;
        VTh[o] = hh;
        VTl[o] = f2bf(v - bf2f(hh));
    }
}

// ---------------- MFMA Retention (R18: R17 + K/V register prefetch) -------
// R17 (in-reg S + cooperative K stage) broke the 160us invariant: 98.5us,
// MfmaUtil 34.5%. Remaining stall: the stage is the ONLY global-load point
// per kt and sits between back-to-back barriers — every wave waits the same
// ~500cyc vmcnt before the ds_writes. R18 = T14 on this structure: issue
// kt+1's 12 short8 loads right after the stage barrier (overlap the ~6Kcyc
// compute), so next kt's ds_writes find data already landed.
// VGPR 84 -> ~132 (+48 prefetch regs), safely under (256,3)'s ~170 cap
// (R16 spilled at the 128 cap of (256,4) — known cliff).
__global__ __launch_bounds__(256, 3) void retention_kernel(
    const us* __restrict__ Qch, const us* __restrict__ Qcl,
    const us* __restrict__ K1h, const us* __restrict__ K1l,
    const us* __restrict__ VTh, const us* __restrict__ VTl,
    float* __restrict__ Pbuf,
    const float* __restrict__ gamma, const float* __restrict__ qk_scale)
{
    constexpr int SPV = 68;            // V row pad (shorts)
    constexpr int SPK = 132;           // K row pad (shorts), 8B-aligned rows
    constexpr int PLV = 64 * SPV;      // 4352 shorts
    constexpr int PLK = 64 * SPK;      // 8448 shorts
    __shared__ us smem[2 * PLK + 2 * PLV];   // 51,200 B
    us* sKh = smem;
    us* sKl = smem + PLK;
    us* sVh = smem + 2 * PLK;
    us* sVl = smem + 2 * PLK + PLV;

    const int tid = threadIdx.x;
    const int w = tid >> 6, lane = tid & 63;
    const int ln = lane & 15, quad = lane >> 4;
    const int r = (int)blockIdx.x >> 4, bh = (int)blockIdx.x & 15;
    const int h = bh & 7;
    int qt, klo, slot;
    if (r == 0)       { qt = 15; klo = 0;  slot = 15; }
    else if (r == 1)  { qt = 31; klo = 16; slot = 47; }
    else if (r <= 17) { qt = 14 + r; klo = 0; slot = 16 + 2 * (qt - 16); }
    else {
        int u = r - 18, s = 15 - (u >> 1);
        if ((u & 1) == 0) { qt = s - 1;  klo = 0;  slot = qt; }
        else              { qt = 15 + s; klo = 16; slot = 17 + 2 * (qt - 16); }
    }
    const int khi = (qt >= 16 && klo == 0) ? 15 : qt;
    const int qc0 = qt * 64;
    const float lg = log2f(gamma[h]);
    const float inv_scale = 1.0f / qk_scale[0];
    const int qloc = w * 16 + ln;                    // this lane's q (tile-local)
    const float rowl = exp2f(lg * (float)qloc);
    const float e16  = exp2f(-16.0f * lg);
    float colq[4];
    #pragma unroll
    for (int r2 = 0; r2 < 4; ++r2)
        colq[r2] = exp2f(-lg * (float)(quad * 4 + r2));

    short8 Qh[4], Ql[4];
    {
        size_t qrow = ((size_t)bh * C_ + qc0 + w * 16 + ln) * 128;
        #pragma unroll
        for (int ck = 0; ck < 4; ++ck) {
            size_t off = qrow + ck * 32 + quad * 8;
            Qh[ck] = *(const short8*)(Qch + off);
            Ql[ck] = *(const short8*)(Qcl + off);
        }
    }
    f32x4 zz = {0.0f, 0.0f, 0.0f, 0.0f};
    f32x4 Or[4], Oi[4];
    #pragma unroll
    for (int it = 0; it < 4; ++it) { Or[it] = zz; Oi[it] = zz; }

    const size_t vtb = (size_t)bh * 64 * C_;
    const int krow_s = tid >> 2, kseg = (tid & 3) * 32;   // K stage coords
    const int vi = tid >> 2, vseg = (tid & 3) * 16;       // V stage coords

    // ---- T14 prefetch registers: next kt's K+V tile (12 short8 = 48 VGPR)
    short8 pkh[4], pkl[4], pvh[2], pvl[2];
    {
        const size_t kb = ((size_t)bh * C_ + klo * 64 + krow_s) * 128 + kseg;
        #pragma unroll
        for (int m = 0; m < 4; ++m) {
            pkh[m] = *(const short8*)(K1h + kb + m * 8);
            pkl[m] = *(const short8*)(K1l + kb + m * 8);
        }
        const size_t g = vtb + (size_t)vi * C_ + klo * 64 + vseg;
        pvh[0] = *(const short8*)(VTh + g);
        pvh[1] = *(const short8*)(VTh + g + 8);
        pvl[0] = *(const short8*)(VTl + g);
        pvl[1] = *(const short8*)(VTl + g + 8);
    }

    for (int kt = klo; kt <= khi; ++kt) {
        const int kc0 = kt * 64;
        __syncthreads();   // all waves done reading sK/sV of kt-1
        {   // ---- write prefetched tile to LDS (loads landed during compute)
            us* dkh = &sKh[krow_s * SPK + kseg];
            us* dkl = &sKl[krow_s * SPK + kseg];
            #pragma unroll
            for (int m = 0; m < 4; ++m) {
                *(short4v*)(dkh + m * 8)     = __builtin_shufflevector(pkh[m], pkh[m], 0, 1, 2, 3);
                *(short4v*)(dkh + m * 8 + 4) = __builtin_shufflevector(pkh[m], pkh[m], 4, 5, 6, 7);
                *(short4v*)(dkl + m * 8)     = __builtin_shufflevector(pkl[m], pkl[m], 0, 1, 2, 3);
                *(short4v*)(dkl + m * 8 + 4) = __builtin_shufflevector(pkl[m], pkl[m], 4, 5, 6, 7);
            }
            *(short4v*)&sVh[vi * SPV + vseg]      = __builtin_shufflevector(pvh[0], pvh[0], 0, 1, 2, 3);
            *(short4v*)&sVh[vi * SPV + vseg + 4]  = __builtin_shufflevector(pvh[0], pvh[0], 4, 5, 6, 7);
            *(short4v*)&sVh[vi * SPV + vseg + 8]  = __builtin_shufflevector(pvh[1], pvh[1], 0, 1, 2, 3);
            *(short4v*)&sVh[vi * SPV + vseg + 12] = __builtin_shufflevector(pvh[1], pvh[1], 4, 5, 6, 7);
            *(short4v*)&sVl[vi * SPV + vseg]      = __builtin_shufflevector(pvl[0], pvl[0], 0, 1, 2, 3);
            *(short4v*)&sVl[vi * SPV + vseg + 4]  = __builtin_shufflevector(pvl[0], pvl[0], 4, 5, 6, 7);
            *(short4v*)&sVl[vi * SPV + vseg + 8]  = __builtin_shufflevector(pvl[1], pvl[1], 0, 1, 2, 3);
            *(short4v*)&sVl[vi * SPV + vseg + 12] = __builtin_shufflevector(pvl[1], pvl[1], 4, 5, 6, 7);
        }
        __syncthreads();   // staged tile ready; no further barrier this kt
        // ---- issue next kt's loads NOW — latency hides under the compute
        if (kt < khi) {
            const size_t kb = ((size_t)bh * C_ + (kc0 + 64) + krow_s) * 128 + kseg;
            #pragma unroll
            for (int m = 0; m < 4; ++m) {
                pkh[m] = *(const short8*)(K1h + kb + m * 8);
                pkl[m] = *(const short8*)(K1l + kb + m * 8);
            }
            const size_t g = vtb + (size_t)vi * C_ + (kc0 + 64) + vseg;
            pvh[0] = *(const short8*)(VTh + g);
            pvh[1] = *(const short8*)(VTh + g + 8);
            pvl[0] = *(const short8*)(VTl + g);
            pvl[1] = *(const short8*)(VTl + g + 8);
        }
        const float tf = exp2f(lg * (float)(qc0 - kc0)) * inv_scale;
        const bool diag = (kt == qt);
        float snt = tf * rowl;
        #pragma unroll
        for (int half = 0; half < 2; ++half) {
            unsigned WRH[2][2], WRL[2][2], WIH[2][2], WIL[2][2];
            #pragma unroll
            for (int n2 = 0; n2 < 2; ++n2) {
                const int nt = half * 2 + n2;
                const int kr = (nt * 16 + ln) * SPK;
                short8 Kh[4], Kl[4];
                #pragma unroll
                for (int ck = 0; ck < 4; ++ck) {
                    Kh[ck] = lds_frag(&sKh[kr + ck * 32 + quad * 8]);
                    Kl[ck] = lds_frag(&sKl[kr + ck * 32 + quad * 8]);
                }
                // swapped QK (R16-verified): S^T = K·Q
                f32x4 sr = zz, si = zz;
                #pragma unroll
                for (int ck = 0; ck < 4; ++ck) {
                    sr = mfma16(Kh[ck], Qh[ck], sr);
                    sr = mfma16(Kl[ck], Qh[ck], sr);
                    sr = mfma16(Kh[ck], Ql[ck], sr);
                }
                short8 nKh2 = negbf(Kh[2]), nKh3 = negbf(Kh[3]);
                short8 nKl2 = negbf(Kl[2]), nKl3 = negbf(Kl[3]);
                si = mfma16(nKh2, Qh[0], si); si = mfma16(nKl2, Qh[0], si); si = mfma16(nKh2, Ql[0], si);
                si = mfma16(nKh3, Qh[1], si); si = mfma16(nKl3, Qh[1], si); si = mfma16(nKh3, Ql[1], si);
                si = mfma16(Kh[0], Qh[2], si); si = mfma16(Kl[0], Qh[2], si); si = mfma16(Kh[0], Ql[2], si);
                si = mfma16(Kh[1], Qh[3], si); si = mfma16(Kl[1], Qh[3], si); si = mfma16(Kh[1], Ql[3], si);
                // decay weight + causal mask in transposed layout (R16-verified):
                // lane holds S[qloc][k = nt*16 + quad*4 + r2]
                float ar[4], ai[4];
                #pragma unroll
                for (int r2 = 0; r2 < 4; ++r2) {
                    float wv = snt * colq[r2];
                    if (diag && (qloc < nt * 16 + quad * 4 + r2)) wv = 0.0f;
                    ar[r2] = sr[r2] * wv;
                    ai[r2] = si[r2] * wv;
                }
                pkhl(ar[0], ar[1], WRH[n2][0], WRL[n2][0]);
                pkhl(ar[2], ar[3], WRH[n2][1], WRL[n2][1]);
                pkhl(ai[0], ai[1], WIH[n2][0], WIL[n2][0]);
                pkhl(ai[2], ai[3], WIH[n2][1], WIL[n2][1]);
                snt *= e16;
            }
            // PV A-frags in-register; V read permuted to match (R16-verified)
            short8 SRH = bcs8(WRH[0][0], WRH[0][1], WRH[1][0], WRH[1][1]);
            short8 SRL = bcs8(WRL[0][0], WRL[0][1], WRL[1][0], WRL[1][1]);
            short8 SIH = bcs8(WIH[0][0], WIH[0][1], WIH[1][0], WIH[1][1]);
            short8 SIL = bcs8(WIL[0][0], WIL[0][1], WIL[1][0], WIL[1][1]);
            #pragma unroll
            for (int it = 0; it < 4; ++it) {
                int vb = (it * 16 + ln) * SPV + half * 32 + quad * 4;
                short8 Vh = lds_fragg(&sVh[vb]);
                short8 Vl = lds_fragg(&sVl[vb]);
                Or[it] = mfma16(SRH, Vh, Or[it]);
                Or[it] = mfma16(SRH, Vl, Or[it]);
                Or[it] = mfma16(SRL, Vh, Or[it]);
                Oi[it] = mfma16(SIH, Vh, Oi[it]);
                Oi[it] = mfma16(SIH, Vl, Oi[it]);
                Oi[it] = mfma16(SIL, Vh, Oi[it]);
            }
        }
    }
    float* Pr = Pbuf + ((size_t)(bh * 48 + slot)) * 8192;
    float* Pi = Pr + 4096;
    #pragma unroll
    for (int it = 0; it < 4; ++it) {
        #pragma unroll
        for (int rr2 = 0; rr2 < 4; ++rr2) {
            int qL = w * 16 + quad * 4 + rr2, iX = it * 16 + ln;
            Pr[qL * 64 + iX] = Or[it][rr2];
            Pi[qL * 64 + iX] = Oi[it][rr2];
        }
    }
}

// -------- Merged: partial reduce + L2 norm -> A1   AND   weight cvt --------
// grid (64, 16): bx<32 -> reduce (qt=bx, bh=by); bx>=32 -> wcvt tile.
__global__ __launch_bounds__(256) void reduce_wcvt_kernel(
    const float* __restrict__ Pbuf,
    us* __restrict__ A1h, us* __restrict__ A1l,
    const float* __restrict__ WG, const float* __restrict__ WO,
    us* __restrict__ Gh, us* __restrict__ Gl,
    us* __restrict__ Oh, us* __restrict__ Ol)
{
    __shared__ float T[32 * 33];
    if ((int)blockIdx.x < 32) {
        const int qt = blockIdx.x, bh = blockIdx.y;
        const int h = bh & 7, b = bh >> 3;
        const int t = threadIdx.x;
        const int q = t >> 2, i0 = (t & 3) * 16;
        const int slot0 = (qt < 16) ? qt : 16 + 2 * (qt - 16);
        const int nparts = (qt < 16) ? 1 : 2;
        const float* P0 = Pbuf + ((size_t)(bh * 48 + slot0)) * 8192 + q * 64 + i0;
        float orv[16], oiv[16];
        #pragma unroll
        for (int s4 = 0; s4 < 4; ++s4) {
            *(float4*)&orv[s4 * 4] = *(const float4*)(P0 + s4 * 4);
            *(float4*)&oiv[s4 * 4] = *(const float4*)(P0 + 4096 + s4 * 4);
        }
        if (nparts == 2) {
            const float* P1 = P0 + 8192;
            #pragma unroll
            for (int s4 = 0; s4 < 4; ++s4) {
                float4 a = *(const float4*)(P1 + s4 * 4);
                float4 c = *(const float4*)(P1 + 4096 + s4 * 4);
                orv[s4 * 4]     += a.x; orv[s4 * 4 + 1] += a.y;
                orv[s4 * 4 + 2] += a.z; orv[s4 * 4 + 3] += a.w;
                oiv[s4 * 4]     += c.x; oiv[s4 * 4 + 1] += c.y;
                oiv[s4 * 4 + 2] += c.z; oiv[s4 * 4 + 3] += c.w;
            }
        }
        float ss = 0.0f;
        #pragma unroll
        for (int k = 0; k < 16; ++k) ss += orv[k] * orv[k] + oiv[k] * oiv[k];
        ss += __shfl_xor(ss, 1);
        ss += __shfl_xor(ss, 2);
        float rn = rsqrtf(ss);
        size_t o = (((size_t)(b * C_ + qt * 64 + q)) * H_ + h) * HW_ + i0;
        us th[16], tl[16];
        #pragma unroll
        for (int k = 0; k < 16; ++k) {
            float v = orv[k] * rn;
            us hh = f2bf(v); th[k] = hh; tl[k] = f2bf(v - bf2f(hh));
        }
        *(short8*)&A1h[o] = *(short8*)&th[0]; *(short8*)&A1h[o + 8] = *(short8*)&th[8];
        *(short8*)&A1l[o] = *(short8*)&tl[0]; *(short8*)&A1l[o + 8] = *(short8*)&tl[8];
        #pragma unroll
        for (int k = 0; k < 16; ++k) {
            float v = oiv[k] * rn;
            us hh = f2bf(v); th[k] = hh; tl[k] = f2bf(v - bf2f(hh));
        }
        *(short8*)&A1h[N1_ + o] = *(short8*)&th[0]; *(short8*)&A1h[N1_ + o + 8] = *(short8*)&th[8];
        *(short8*)&A1l[N1_ + o] = *(short8*)&tl[0]; *(short8*)&A1l[N1_ + o + 8] = *(short8*)&tl[8];
    } else {
        int widx = ((int)blockIdx.x - 32) * 16 + (int)blockIdx.y;  // 0..511
        int z = widx >> 8, w2 = widx & 255;
        const float* src = z ? WO : WG;
        us* dh = z ? Oh : Gh;
        us* dl = z ? Ol : Gl;
        int k0 = (w2 >> 4) * 32, n0 = (w2 & 15) * 32;
        int c = threadIdx.x & 31, r8 = threadIdx.x >> 5;
        #pragma unroll
        for (int rr = 0; rr < 4; ++rr) {
            int rw = r8 * 4 + rr;
            T[rw * 33 + c] = src[(size_t)(k0 + rw) * 512 + n0 + c];
        }
        __syncthreads();
        #pragma unroll
        for (int rr = 0; rr < 4; ++rr) {
            int rw = r8 * 4 + rr;           // n-local
            float v = T[c * 33 + rw];       // [k-local=c][n-local=rw]
            us hh = f2bf(v);
            size_t o = (size_t)(n0 + rw) * 512 + k0 + c;
            dh[o] = hh; dl[o] = f2bf(v - bf2f(hh));
        }
    }
}

// ------- Fused G-GEMM + complex gate: A2 = gate(A1, A1*WG) -----------------
__global__ __launch_bounds__(256) void gemm_gate_kernel(
    const us* __restrict__ Ah, const us* __restrict__ Al,
    const us* __restrict__ BTh, const us* __restrict__ BTl,
    us* __restrict__ A2h, us* __restrict__ A2l)
{
    const int tid = threadIdx.x;
    const int w = tid >> 6, lane = tid & 63;
    const int ln = lane & 15, quad = lane >> 4;
    const int bm = blockIdx.x * 128 + w * 32;   // re-plane rows [0,4096)
    const int bn = blockIdx.y * 64;
    f32x4 accR[2][4], accI[2][4];
    #pragma unroll
    for (int mt = 0; mt < 2; ++mt)
        #pragma unroll
        for (int nt = 0; nt < 4; ++nt) {
            accR[mt][nt] = (f32x4){0.f, 0.f, 0.f, 0.f};
            accI[mt][nt] = (f32x4){0.f, 0.f, 0.f, 0.f};
        }
    const us* pAr[2][2];
    const us* pAi[2][2];
    const us* pB[4][2];
    #pragma unroll
    for (int mt = 0; mt < 2; ++mt) {
        size_t rr = (size_t)(bm + mt * 16 + ln) * 512 + quad * 8;
        pAr[mt][0] = Ah + rr;        pAr[mt][1] = Al + rr;
        pAi[mt][0] = Ah + N1_ + rr;  pAi[mt][1] = Al + N1_ + rr;
    }
    #pragma unroll
    for (int nt = 0; nt < 4; ++nt) {
        size_t rr = (size_t)(bn + nt * 16 + ln) * 512 + quad * 8;
        pB[nt][0] = BTh + rr; pB[nt][1] = BTl + rr;
    }
    #pragma unroll 4
    for (int ks = 0; ks < 16; ++ks) {
        const int ko = ks * 32;
        short8 Ar[2][2], Ai[2][2], Bf[4][2];
        #pragma unroll
        for (int mt = 0; mt < 2; ++mt) {
            Ar[mt][0] = *(const short8*)(pAr[mt][0] + ko);
            Ar[mt][1] = *(const short8*)(pAr[mt][1] + ko);
            Ai[mt][0] = *(const short8*)(pAi[mt][0] + ko);
            Ai[mt][1] = *(const short8*)(pAi[mt][1] + ko);
        }
        #pragma unroll
        for (int nt = 0; nt < 4; ++nt) {
            Bf[nt][0] = *(const short8*)(pB[nt][0] + ko);
            Bf[nt][1] = *(const short8*)(pB[nt][1] + ko);
        }
        #pragma unroll
        for (int mt = 0; mt < 2; ++mt)
            #pragma unroll
            for (int nt = 0; nt < 4; ++nt) {
                accR[mt][nt] = mfma16(Ar[mt][0], Bf[nt][0], accR[mt][nt]);
                accR[mt][nt] = mfma16(Ar[mt][0], Bf[nt][1], accR[mt][nt]);
                accR[mt][nt] = mfma16(Ar[mt][1], Bf[nt][0], accR[mt][nt]);
                accI[mt][nt] = mfma16(Ai[mt][0], Bf[nt][0], accI[mt][nt]);
                accI[mt][nt] = mfma16(Ai[mt][0], Bf[nt][1], accI[mt][nt]);
                accI[mt][nt] = mfma16(Ai[mt][1], Bf[nt][0], accI[mt][nt]);
            }
    }
    #pragma unroll
    for (int mt = 0; mt < 2; ++mt)
        #pragma unroll
        for (int nt = 0; nt < 4; ++nt)
            #pragma unroll
            for (int r = 0; r < 4; ++r) {
                int m = bm + mt * 16 + quad * 4 + r;
                int n = bn + nt * 16 + ln;
                size_t idx = (size_t)m * 512 + n;
                float gr = accR[mt][nt][r], gi = accI[mt][nt][r];
                float hr = bf2f(Ah[idx]) + bf2f(Al[idx]);
                float hi = bf2f(Ah[N1_ + idx]) + bf2f(Al[N1_ + idx]);
                float e = expf(-2.0f * gr);
                float sn, cs;
                sincosf(2.0f * gi, &sn, &cs);
                float dr = 1.0f + e * cs;
                float di = -e * sn;
                float nr = hr * gr - hi * gi;
                float ni = hr * gi + hi * gr;
                float inv = 1.0f / (dr * dr + di * di);
                float o2r = (nr * dr + ni * di) * inv;
                float o2i = (ni * dr - nr * di) * inv;
                us t = f2bf(o2r);
                A2h[idx] = t; A2l[idx] = f2bf(o2r - bf2f(t));
                t = f2bf(o2i);
                A2h[N1_ + idx] = t; A2l[N1_ + idx] = f2bf(o2i - bf2f(t));
            }
}

// ---------------- split-bf16 MFMA GEMM: C[8192,512] = A * W (WT given) -----
__global__ __launch_bounds__(256) void gemm_mfma_kernel(
    const us* __restrict__ Ah, const us* __restrict__ Al,
    const us* __restrict__ BTh, const us* __restrict__ BTl,
    float* __restrict__ Cout, int mode)
{
    const int tid = threadIdx.x;
    const int w = tid >> 6, lane = tid & 63;
    const int ln = lane & 15, quad = lane >> 4;
    const int bm = blockIdx.x * 128 + w * 32;
    const int bn = blockIdx.y * 64;
    f32x4 acc[2][4];
    #pragma unroll
    for (int mt = 0; mt < 2; ++mt)
        #pragma unroll
        for (int nt = 0; nt < 4; ++nt) acc[mt][nt] = (f32x4){0.f, 0.f, 0.f, 0.f};
    const us* pA[2][2];
    const us* pB[4][2];
    #pragma unroll
    for (int mt = 0; mt < 2; ++mt) {
        size_t r = (size_t)(bm + mt * 16 + ln) * 512 + quad * 8;
        pA[mt][0] = Ah + r; pA[mt][1] = Al + r;
    }
    #pragma unroll
    for (int nt = 0; nt < 4; ++nt) {
        size_t r = (size_t)(bn + nt * 16 + ln) * 512 + quad * 8;
        pB[nt][0] = BTh + r; pB[nt][1] = BTl + r;
    }
    #pragma unroll
    for (int ks = 0; ks < 16; ++ks) {
        const int ko = ks * 32;
        short8 Af[2][2], Bf[4][2];
        #pragma unroll
        for (int mt = 0; mt < 2; ++mt) {
            Af[mt][0] = *(const short8*)(pA[mt][0] + ko);
            Af[mt][1] = *(const short8*)(pA[mt][1] + ko);
        }
        #pragma unroll
        for (int nt = 0; nt < 4; ++nt) {
            Bf[nt][0] = *(const short8*)(pB[nt][0] + ko);
            Bf[nt][1] = *(const short8*)(pB[nt][1] + ko);
        }
        #pragma unroll
        for (int mt = 0; mt < 2; ++mt)
            #pragma unroll
            for (int nt = 0; nt < 4; ++nt) {
                acc[mt][nt] = mfma16(Af[mt][0], Bf[nt][0], acc[mt][nt]);
                acc[mt][nt] = mfma16(Af[mt][0], Bf[nt][1], acc[mt][nt]);
                acc[mt][nt] = mfma16(Af[mt][1], Bf[nt][0], acc[mt][nt]);
            }
    }
    #pragma unroll
    for (int mt = 0; mt < 2; ++mt)
        #pragma unroll
        for (int nt = 0; nt < 4; ++nt)
            #pragma unroll
            for (int r = 0; r < 4; ++r) {
                int m = bm + mt * 16 + quad * 4 + r;
                int n = bn + nt * 16 + ln;
                float v = acc[mt][nt][r];
                if (mode == 0) {
                    Cout[(size_t)m * 512 + n] = v;
                } else if (mode == 1) {
                    if (m < 4096) Cout[2 * ((size_t)m * 512 + n)] = v;
                    else          Cout[2 * ((size_t)(m - 4096) * 512 + n) + 1] = v;
                } else {
                    if (m < 4096) Cout[(size_t)m * 512 + n] = v;
                }
            }
}

extern "C" void kernel_launch(void* const* d_in, const int* in_sizes, int n_in,
                              void* d_out, int out_size, void* d_ws, size_t ws_size,
                              hipStream_t stream)
{
    const float* x     = (const float*)d_in[0];
    const float* WQ    = (const float*)d_in[1];
    const float* WK    = (const float*)d_in[2];
    const float* WV    = (const float*)d_in[3];
    const float* theta = (const float*)d_in[4];
    const float* gamma = (const float*)d_in[5];
    const float* qk    = (const float*)d_in[7];
    const float* WO    = (const float*)d_in[8];
    const float* WG    = (const float*)d_in[9];
    float* out = (float*)d_out;

    const size_t N1 = (size_t)B_ * H_ * C_ * HW_;       // 2,097,152
    const size_t SQ = (size_t)B_ * H_ * C_ * 128;       // 4,194,304 shorts
    const size_t SV = (size_t)B_ * H_ * HW_ * C_;       // 2,097,152 shorts
    us* usw = (us*)d_ws;
    us *Qch = usw,            *Qcl = usw + SQ,
       *K1h = usw + 2 * SQ,   *K1l = usw + 3 * SQ,
       *VTh = usw + 4 * SQ,   *VTl = usw + 4 * SQ + SV; // shorts end at 5*N1 floats
    float* fw = (float*)d_ws;
    us *A1h = (us*)(fw + 5 * N1), *A1l = (us*)(fw + 6 * N1);
    // WT overlays dead K1 (wcvt blocks run after retention):
    us *WTGh = K1h,            *WTGl = K1h + 262144,
       *WTOh = K1h + 524288,  *WTOl = K1h + 786432;
    us *A2h = (us*)(fw + 9 * N1), *A2l = (us*)(fw + 10 * N1);
    // Pbuf = 3*N1 floats (768 x 8192) spans [7N1,10N1): dead before
    // gemm_gate writes A2 (9N1..11N1) — reduce consumed it already.
    float *Pbuf = fw + 7 * N1;

    proj_kernel<<<dim3(C_ / 32, B_ * H_), 256, 0, stream>>>(
        x, WQ, WK, WV, theta, Qch, Qcl, K1h, K1l, VTh, VTl);
    retention_kernel<<<dim3(768), 256, 0, stream>>>(
        Qch, Qcl, K1h, K1l, VTh, VTl, Pbuf, gamma, qk);
    reduce_wcvt_kernel<<<dim3(64, 16), 256, 0, stream>>>(
        Pbuf, A1h, A1l, WG, WO, WTGh, WTGl, WTOh, WTOl);

    gemm_gate_kernel<<<dim3(32, 8), 256, 0, stream>>>(
        A1h, A1l, WTGh, WTGl, A2h, A2l);

    int outmode = (out_size >= (int)(2 * N1)) ? 1 : 2;
    gemm_mfma_kernel<<<dim3(64, 8), 256, 0, stream>>>(
        A2h, A2l, WTOh, WTOl, out, outmode);
}

// Round 10
// 318.382 us; speedup vs baseline: 1.0740x; 1.0740x over previous
//
#include <hip/hip_runtime.h>
#include <cstdint>
#include <cstddef>

#define B_  2
#define H_  8
#define C_  2048
#define HW_ 64
#define HD_ 512   // H_*HW_
#define N1_ 2097152  // B_*H_*C_*HW_

typedef __attribute__((ext_vector_type(8))) short short8;
typedef __attribute__((ext_vector_type(4))) short short4v;
typedef __attribute__((ext_vector_type(4))) float f32x4;
typedef __attribute__((ext_vector_type(4))) int   int4v;
typedef unsigned short us;

static __device__ inline us f2bf(float f) {           // RNE
    unsigned u = __builtin_bit_cast(unsigned, f);
    u = u + 0x7FFFu + ((u >> 16) & 1u);
    return (us)(u >> 16);
}
static __device__ inline us f2bf_t(float f) {         // truncate (hot path)
    return (us)(__builtin_bit_cast(unsigned, f) >> 16);
}
static __device__ inline float bf2f(us s) {
    unsigned u = ((unsigned)s) << 16;
    return __builtin_bit_cast(float, u);
}
static __device__ inline f32x4 mfma16(short8 a, short8 b, f32x4 c) {
    return __builtin_amdgcn_mfma_f32_16x16x32_bf16(a, b, c, 0, 0, 0);
}
static __device__ inline short8 negbf(short8 v) {
    int4v u = __builtin_bit_cast(int4v, v);
    u ^= (int)0x80008000;
    return __builtin_bit_cast(short8, u);
}
// b64-pair LDS fragment load (rows padded -> 8B-aligned only)
static __device__ inline short8 lds_frag(const us* p) {
    short4v a = *(const short4v*)p;
    short4v b = *(const short4v*)(p + 4);
    return __builtin_shufflevector(a, b, 0, 1, 2, 3, 4, 5, 6, 7);
}
// V fragment read for permuted PV contraction (R16-verified): 8B at +0, +16
static __device__ inline short8 lds_fragg(const us* p) {
    short4v a = *(const short4v*)p;
    short4v b = *(const short4v*)(p + 16);
    return __builtin_shufflevector(a, b, 0, 1, 2, 3, 4, 5, 6, 7);
}
// pack two f32 into bf16x2 high word + bf16x2 residual word (R16-verified)
static __device__ inline void pkhl(float a, float b, unsigned &hw, unsigned &lw) {
    us ha = f2bf_t(a), hb = f2bf_t(b);
    hw = (unsigned)ha | ((unsigned)hb << 16);
    float la = a - bf2f(ha), lb = b - bf2f(hb);
    lw = (unsigned)f2bf_t(la) | ((unsigned)f2bf_t(lb) << 16);
}
static __device__ inline short8 bcs8(unsigned a, unsigned b, unsigned c, unsigned d) {
    int4v v = {(int)a, (int)b, (int)c, (int)d};
    return __builtin_bit_cast(short8, v);
}

// ---------------- Projection + rotary phase ----------------
__global__ __launch_bounds__(256) void proj_kernel(
    const float* __restrict__ x, const float* __restrict__ WQ,
    const float* __restrict__ WK, const float* __restrict__ WV,
    const float* __restrict__ theta,
    us* __restrict__ Qch, us* __restrict__ Qcl,
    us* __restrict__ K1h, us* __restrict__ K1l,
    us* __restrict__ VTh, us* __restrict__ VTl)
{
    __shared__ float smem[3 * 64 * 68 + 32 * 68];   // 60,928 B
    float* sWT = smem;               // [3][64 j][68 i]
    float* sx  = smem + 3 * 64 * 68; // [32 c][68 i]
    int tid = threadIdx.x;
    int bh = blockIdx.y; int h = bh & 7;
    int c0 = blockIdx.x * 32;
    for (int t = tid; t < 1024; t += 256) {
        int j4 = (t & 15) * 4, i = t >> 4;
        float4 wq = *(const float4*)&WQ[(h * 64 + i) * 64 + j4];
        float4 wk = *(const float4*)&WK[(h * 64 + i) * 64 + j4];
        float4 wv = *(const float4*)&WV[(h * 64 + i) * 64 + j4];
        sWT[(j4 + 0) * 68 + i] = wq.x; sWT[(j4 + 1) * 68 + i] = wq.y;
        sWT[(j4 + 2) * 68 + i] = wq.z; sWT[(j4 + 3) * 68 + i] = wq.w;
        sWT[64 * 68 + (j4 + 0) * 68 + i] = wk.x; sWT[64 * 68 + (j4 + 1) * 68 + i] = wk.y;
        sWT[64 * 68 + (j4 + 2) * 68 + i] = wk.z; sWT[64 * 68 + (j4 + 3) * 68 + i] = wk.w;
        sWT[2 * 64 * 68 + (j4 + 0) * 68 + i] = wv.x; sWT[2 * 64 * 68 + (j4 + 1) * 68 + i] = wv.y;
        sWT[2 * 64 * 68 + (j4 + 2) * 68 + i] = wv.z; sWT[2 * 64 * 68 + (j4 + 3) * 68 + i] = wv.w;
    }
    for (int t = tid; t < 512; t += 256) {
        int i4 = (t & 15) * 4, c = t >> 4;
        *(float4*)&sx[c * 68 + i4] =
            *(const float4*)&x[((size_t)((bh >> 3) * C_ + c0 + c)) * HD_ + h * 64 + i4];
    }
    __syncthreads();
    int j = tid & 63, cg = tid >> 6;     // cg uniform per wave
    float aq[8] = {}, ak[8] = {}, av[8] = {};
    const float* pw0 = &sWT[j * 68];
    const float* pw1 = &sWT[64 * 68 + j * 68];
    const float* pw2 = &sWT[2 * 64 * 68 + j * 68];
    const float* px  = &sx[cg * 8 * 68];
    #pragma unroll 2
    for (int i0 = 0; i0 < 64; i0 += 4) {
        float4 w0 = *(const float4*)(pw0 + i0);
        float4 w1 = *(const float4*)(pw1 + i0);
        float4 w2 = *(const float4*)(pw2 + i0);
        #pragma unroll
        for (int cc = 0; cc < 8; ++cc) {
            float4 xv = *(const float4*)(px + cc * 68 + i0);
            aq[cc] += xv.x * w0.x + xv.y * w0.y + xv.z * w0.z + xv.w * w0.w;
            ak[cc] += xv.x * w1.x + xv.y * w1.y + xv.z * w1.z + xv.w * w1.w;
            av[cc] += xv.x * w2.x + xv.y * w2.y + xv.z * w2.z + xv.w * w2.w;
        }
    }
    float th = theta[h * 64 + j];
    #pragma unroll
    for (int cc = 0; cc < 8; ++cc) {
        int c = c0 + cg * 8 + cc;
        float sn, cs;
        sincosf((float)c * th, &sn, &cs);
        float qr = aq[cc] * cs, qi = aq[cc] * sn;
        float kr = ak[cc] * cs, nki = ak[cc] * sn;   // nki = -Ki
        size_t rq = ((size_t)bh * C_ + c) * 128;
        us h0;
        h0 = f2bf(qr);  Qch[rq + j]      = h0; Qcl[rq + j]      = f2bf(qr  - bf2f(h0));
        h0 = f2bf(qi);  Qch[rq + 64 + j] = h0; Qcl[rq + 64 + j] = f2bf(qi  - bf2f(h0));
        h0 = f2bf(kr);  K1h[rq + j]      = h0; K1l[rq + j]      = f2bf(kr  - bf2f(h0));
        h0 = f2bf(nki); K1h[rq + 64 + j] = h0; K1l[rq + 64 + j] = f2bf(nki - bf2f(h0));
    }
    __syncthreads();
    float* T0 = smem;                   // [64][33]
    #pragma unroll
    for (int cc = 0; cc < 8; ++cc)
        T0[j * 33 + cg * 8 + cc] = av[cc];
    __syncthreads();
    int cc2 = tid & 31, jg = tid >> 5;
    #pragma unroll
    for (int jj = 0; jj < 8; ++jj) {
        int jr = jg * 8 + jj;
        float v = T0[jr * 33 + cc2];
        us hh = f2bf(v);
        size_t o = ((size_t)bh * 64 + jr) * C_ + c0 + cc2;
        VTh[o] = hh;
        VTl[o] = f2bf(v - bf2f(hh));
    }
}

// ---------------- MFMA Retention (R17 VERBATIM — proven 98.5us) -----------
// R17: in-reg S (swapped QK, R16-verified) + cooperative K stage. 98.5us,
// MfmaUtil 34.5%. R18's prefetch-across-barrier SPILLED (WRITE +194MB
// scratch, 139us) — twice-falsified (R16, R18); do not reintroduce.
__global__ __launch_bounds__(256, 3) void retention_kernel(
    const us* __restrict__ Qch, const us* __restrict__ Qcl,
    const us* __restrict__ K1h, const us* __restrict__ K1l,
    const us* __restrict__ VTh, const us* __restrict__ VTl,
    float* __restrict__ Pbuf,
    const float* __restrict__ gamma, const float* __restrict__ qk_scale)
{
    constexpr int SPV = 68;            // V row pad (shorts)
    constexpr int SPK = 132;           // K row pad (shorts), 8B-aligned rows
    constexpr int PLV = 64 * SPV;      // 4352 shorts
    constexpr int PLK = 64 * SPK;      // 8448 shorts
    __shared__ us smem[2 * PLK + 2 * PLV];   // 51,200 B
    us* sKh = smem;
    us* sKl = smem + PLK;
    us* sVh = smem + 2 * PLK;
    us* sVl = smem + 2 * PLK + PLV;

    const int tid = threadIdx.x;
    const int w = tid >> 6, lane = tid & 63;
    const int ln = lane & 15, quad = lane >> 4;
    const int r = (int)blockIdx.x >> 4, bh = (int)blockIdx.x & 15;
    const int h = bh & 7;
    int qt, klo, slot;
    if (r == 0)       { qt = 15; klo = 0;  slot = 15; }
    else if (r == 1)  { qt = 31; klo = 16; slot = 47; }
    else if (r <= 17) { qt = 14 + r; klo = 0; slot = 16 + 2 * (qt - 16); }
    else {
        int u = r - 18, s = 15 - (u >> 1);
        if ((u & 1) == 0) { qt = s - 1;  klo = 0;  slot = qt; }
        else              { qt = 15 + s; klo = 16; slot = 17 + 2 * (qt - 16); }
    }
    const int khi = (qt >= 16 && klo == 0) ? 15 : qt;
    const int qc0 = qt * 64;
    const float lg = log2f(gamma[h]);
    const float inv_scale = 1.0f / qk_scale[0];
    const int qloc = w * 16 + ln;                    // this lane's q (tile-local)
    const float rowl = exp2f(lg * (float)qloc);
    const float e16  = exp2f(-16.0f * lg);
    float colq[4];
    #pragma unroll
    for (int r2 = 0; r2 < 4; ++r2)
        colq[r2] = exp2f(-lg * (float)(quad * 4 + r2));

    short8 Qh[4], Ql[4];
    {
        size_t qrow = ((size_t)bh * C_ + qc0 + w * 16 + ln) * 128;
        #pragma unroll
        for (int ck = 0; ck < 4; ++ck) {
            size_t off = qrow + ck * 32 + quad * 8;
            Qh[ck] = *(const short8*)(Qch + off);
            Ql[ck] = *(const short8*)(Qcl + off);
        }
    }
    f32x4 zz = {0.0f, 0.0f, 0.0f, 0.0f};
    f32x4 Or[4], Oi[4];
    #pragma unroll
    for (int it = 0; it < 4; ++it) { Or[it] = zz; Oi[it] = zz; }

    const size_t vtb = (size_t)bh * 64 * C_;
    const int krow_s = tid >> 2, kseg = (tid & 3) * 32;   // K stage coords
    const int vi = tid >> 2, vseg = (tid & 3) * 16;       // V stage coords

    for (int kt = klo; kt <= khi; ++kt) {
        const int kc0 = kt * 64;
        __syncthreads();   // all waves done reading sK/sV of kt-1
        {   // ---- cooperative stage: K (once per block!) + V, all loads together
            const size_t kb = ((size_t)bh * C_ + kc0 + krow_s) * 128 + kseg;
            const us* gh = K1h + kb;
            const us* gl = K1l + kb;
            us* dkh = &sKh[krow_s * SPK + kseg];
            us* dkl = &sKl[krow_s * SPK + kseg];
            #pragma unroll
            for (int m = 0; m < 4; ++m) {
                short8 a = *(const short8*)(gh + m * 8);
                *(short4v*)(dkh + m * 8)     = __builtin_shufflevector(a, a, 0, 1, 2, 3);
                *(short4v*)(dkh + m * 8 + 4) = __builtin_shufflevector(a, a, 4, 5, 6, 7);
                a = *(const short8*)(gl + m * 8);
                *(short4v*)(dkl + m * 8)     = __builtin_shufflevector(a, a, 0, 1, 2, 3);
                *(short4v*)(dkl + m * 8 + 4) = __builtin_shufflevector(a, a, 4, 5, 6, 7);
            }
            size_t g = vtb + (size_t)vi * C_ + kc0 + vseg;
            short8 a = *(const short8*)(VTh + g);
            short8 bq = *(const short8*)(VTh + g + 8);
            *(short4v*)&sVh[vi * SPV + vseg]      = __builtin_shufflevector(a, a, 0, 1, 2, 3);
            *(short4v*)&sVh[vi * SPV + vseg + 4]  = __builtin_shufflevector(a, a, 4, 5, 6, 7);
            *(short4v*)&sVh[vi * SPV + vseg + 8]  = __builtin_shufflevector(bq, bq, 0, 1, 2, 3);
            *(short4v*)&sVh[vi * SPV + vseg + 12] = __builtin_shufflevector(bq, bq, 4, 5, 6, 7);
            a  = *(const short8*)(VTl + g);
            bq = *(const short8*)(VTl + g + 8);
            *(short4v*)&sVl[vi * SPV + vseg]      = __builtin_shufflevector(a, a, 0, 1, 2, 3);
            *(short4v*)&sVl[vi * SPV + vseg + 4]  = __builtin_shufflevector(a, a, 4, 5, 6, 7);
            *(short4v*)&sVl[vi * SPV + vseg + 8]  = __builtin_shufflevector(bq, bq, 0, 1, 2, 3);
            *(short4v*)&sVl[vi * SPV + vseg + 12] = __builtin_shufflevector(bq, bq, 4, 5, 6, 7);
        }
        __syncthreads();   // staged tile ready; no further barrier this kt
        const float tf = exp2f(lg * (float)(qc0 - kc0)) * inv_scale;
        const bool diag = (kt == qt);
        float snt = tf * rowl;
        #pragma unroll
        for (int half = 0; half < 2; ++half) {
            unsigned WRH[2][2], WRL[2][2], WIH[2][2], WIL[2][2];
            #pragma unroll
            for (int n2 = 0; n2 < 2; ++n2) {
                const int nt = half * 2 + n2;
                const int kr = (nt * 16 + ln) * SPK;
                short8 Kh[4], Kl[4];
                #pragma unroll
                for (int ck = 0; ck < 4; ++ck) {
                    Kh[ck] = lds_frag(&sKh[kr + ck * 32 + quad * 8]);
                    Kl[ck] = lds_frag(&sKl[kr + ck * 32 + quad * 8]);
                }
                // swapped QK (R16-verified): S^T = K·Q
                f32x4 sr = zz, si = zz;
                #pragma unroll
                for (int ck = 0; ck < 4; ++ck) {
                    sr = mfma16(Kh[ck], Qh[ck], sr);
                    sr = mfma16(Kl[ck], Qh[ck], sr);
                    sr = mfma16(Kh[ck], Ql[ck], sr);
                }
                short8 nKh2 = negbf(Kh[2]), nKh3 = negbf(Kh[3]);
                short8 nKl2 = negbf(Kl[2]), nKl3 = negbf(Kl[3]);
                si = mfma16(nKh2, Qh[0], si); si = mfma16(nKl2, Qh[0], si); si = mfma16(nKh2, Ql[0], si);
                si = mfma16(nKh3, Qh[1], si); si = mfma16(nKl3, Qh[1], si); si = mfma16(nKh3, Ql[1], si);
                si = mfma16(Kh[0], Qh[2], si); si = mfma16(Kl[0], Qh[2], si); si = mfma16(Kh[0], Ql[2], si);
                si = mfma16(Kh[1], Qh[3], si); si = mfma16(Kl[1], Qh[3], si); si = mfma16(Kh[1], Ql[3], si);
                // decay weight + causal mask in transposed layout (R16-verified):
                // lane holds S[qloc][k = nt*16 + quad*4 + r2]
                float ar[4], ai[4];
                #pragma unroll
                for (int r2 = 0; r2 < 4; ++r2) {
                    float wv = snt * colq[r2];
                    if (diag && (qloc < nt * 16 + quad * 4 + r2)) wv = 0.0f;
                    ar[r2] = sr[r2] * wv;
                    ai[r2] = si[r2] * wv;
                }
                pkhl(ar[0], ar[1], WRH[n2][0], WRL[n2][0]);
                pkhl(ar[2], ar[3], WRH[n2][1], WRL[n2][1]);
                pkhl(ai[0], ai[1], WIH[n2][0], WIL[n2][0]);
                pkhl(ai[2], ai[3], WIH[n2][1], WIL[n2][1]);
                snt *= e16;
            }
            // PV A-frags in-register; V read permuted to match (R16-verified)
            short8 SRH = bcs8(WRH[0][0], WRH[0][1], WRH[1][0], WRH[1][1]);
            short8 SRL = bcs8(WRL[0][0], WRL[0][1], WRL[1][0], WRL[1][1]);
            short8 SIH = bcs8(WIH[0][0], WIH[0][1], WIH[1][0], WIH[1][1]);
            short8 SIL = bcs8(WIL[0][0], WIL[0][1], WIL[1][0], WIL[1][1]);
            #pragma unroll
            for (int it = 0; it < 4; ++it) {
                int vb = (it * 16 + ln) * SPV + half * 32 + quad * 4;
                short8 Vh = lds_fragg(&sVh[vb]);
                short8 Vl = lds_fragg(&sVl[vb]);
                Or[it] = mfma16(SRH, Vh, Or[it]);
                Or[it] = mfma16(SRH, Vl, Or[it]);
                Or[it] = mfma16(SRL, Vh, Or[it]);
                Oi[it] = mfma16(SIH, Vh, Oi[it]);
                Oi[it] = mfma16(SIH, Vl, Oi[it]);
                Oi[it] = mfma16(SIL, Vh, Oi[it]);
            }
        }
    }
    float* Pr = Pbuf + ((size_t)(bh * 48 + slot)) * 8192;
    float* Pi = Pr + 4096;
    #pragma unroll
    for (int it = 0; it < 4; ++it) {
        #pragma unroll
        for (int rr2 = 0; rr2 < 4; ++rr2) {
            int qL = w * 16 + quad * 4 + rr2, iX = it * 16 + ln;
            Pr[qL * 64 + iX] = Or[it][rr2];
            Pi[qL * 64 + iX] = Oi[it][rr2];
        }
    }
}

// -------- Merged: partial reduce + L2 norm -> A1   AND   weight cvt --------
// grid (64, 16): bx<32 -> reduce (qt=bx, bh=by); bx>=32 -> wcvt tile.
__global__ __launch_bounds__(256) void reduce_wcvt_kernel(
    const float* __restrict__ Pbuf,
    us* __restrict__ A1h, us* __restrict__ A1l,
    const float* __restrict__ WG, const float* __restrict__ WO,
    us* __restrict__ Gh, us* __restrict__ Gl,
    us* __restrict__ Oh, us* __restrict__ Ol)
{
    __shared__ float T[32 * 33];
    if ((int)blockIdx.x < 32) {
        const int qt = blockIdx.x, bh = blockIdx.y;
        const int h = bh & 7, b = bh >> 3;
        const int t = threadIdx.x;
        const int q = t >> 2, i0 = (t & 3) * 16;
        const int slot0 = (qt < 16) ? qt : 16 + 2 * (qt - 16);
        const int nparts = (qt < 16) ? 1 : 2;
        const float* P0 = Pbuf + ((size_t)(bh * 48 + slot0)) * 8192 + q * 64 + i0;
        float orv[16], oiv[16];
        #pragma unroll
        for (int s4 = 0; s4 < 4; ++s4) {
            *(float4*)&orv[s4 * 4] = *(const float4*)(P0 + s4 * 4);
            *(float4*)&oiv[s4 * 4] = *(const float4*)(P0 + 4096 + s4 * 4);
        }
        if (nparts == 2) {
            const float* P1 = P0 + 8192;
            #pragma unroll
            for (int s4 = 0; s4 < 4; ++s4) {
                float4 a = *(const float4*)(P1 + s4 * 4);
                float4 c = *(const float4*)(P1 + 4096 + s4 * 4);
                orv[s4 * 4]     += a.x; orv[s4 * 4 + 1] += a.y;
                orv[s4 * 4 + 2] += a.z; orv[s4 * 4 + 3] += a.w;
                oiv[s4 * 4]     += c.x; oiv[s4 * 4 + 1] += c.y;
                oiv[s4 * 4 + 2] += c.z; oiv[s4 * 4 + 3] += c.w;
            }
        }
        float ss = 0.0f;
        #pragma unroll
        for (int k = 0; k < 16; ++k) ss += orv[k] * orv[k] + oiv[k] * oiv[k];
        ss += __shfl_xor(ss, 1);
        ss += __shfl_xor(ss, 2);
        float rn = rsqrtf(ss);
        size_t o = (((size_t)(b * C_ + qt * 64 + q)) * H_ + h) * HW_ + i0;
        us th[16], tl[16];
        #pragma unroll
        for (int k = 0; k < 16; ++k) {
            float v = orv[k] * rn;
            us hh = f2bf(v); th[k] = hh; tl[k] = f2bf(v - bf2f(hh));
        }
        *(short8*)&A1h[o] = *(short8*)&th[0]; *(short8*)&A1h[o + 8] = *(short8*)&th[8];
        *(short8*)&A1l[o] = *(short8*)&tl[0]; *(short8*)&A1l[o + 8] = *(short8*)&tl[8];
        #pragma unroll
        for (int k = 0; k < 16; ++k) {
            float v = oiv[k] * rn;
            us hh = f2bf(v); th[k] = hh; tl[k] = f2bf(v - bf2f(hh));
        }
        *(short8*)&A1h[N1_ + o] = *(short8*)&th[0]; *(short8*)&A1h[N1_ + o + 8] = *(short8*)&th[8];
        *(short8*)&A1l[N1_ + o] = *(short8*)&tl[0]; *(short8*)&A1l[N1_ + o + 8] = *(short8*)&tl[8];
    } else {
        int widx = ((int)blockIdx.x - 32) * 16 + (int)blockIdx.y;  // 0..511
        int z = widx >> 8, w2 = widx & 255;
        const float* src = z ? WO : WG;
        us* dh = z ? Oh : Gh;
        us* dl = z ? Ol : Gl;
        int k0 = (w2 >> 4) * 32, n0 = (w2 & 15) * 32;
        int c = threadIdx.x & 31, r8 = threadIdx.x >> 5;
        #pragma unroll
        for (int rr = 0; rr < 4; ++rr) {
            int rw = r8 * 4 + rr;
            T[rw * 33 + c] = src[(size_t)(k0 + rw) * 512 + n0 + c];
        }
        __syncthreads();
        #pragma unroll
        for (int rr = 0; rr < 4; ++rr) {
            int rw = r8 * 4 + rr;           // n-local
            float v = T[c * 33 + rw];       // [k-local=c][n-local=rw]
            us hh = f2bf(v);
            size_t o = (size_t)(n0 + rw) * 512 + k0 + c;
            dh[o] = hh; dl[o] = f2bf(v - bf2f(hh));
        }
    }
}

// ------- Fused G-GEMM + complex gate: A2 = gate(A1, A1*WG) -----------------
// R19: M-tile halved 128->64 (mt dim removed), grid.x doubled 32->64.
// Old grid(32,8)=256 blocks = 1 block/CU = 1 wave/SIMD — zero TLP to hide
// the K-loop's global-load latency. Now 512 blocks = 2/CU = 2 waves/SIMD.
__global__ __launch_bounds__(256) void gemm_gate_kernel(
    const us* __restrict__ Ah, const us* __restrict__ Al,
    const us* __restrict__ BTh, const us* __restrict__ BTl,
    us* __restrict__ A2h, us* __restrict__ A2l)
{
    const int tid = threadIdx.x;
    const int w = tid >> 6, lane = tid & 63;
    const int ln = lane & 15, quad = lane >> 4;
    const int bm = blockIdx.x * 64 + w * 16;   // re-plane rows [0,4096)
    const int bn = blockIdx.y * 64;
    f32x4 accR[4], accI[4];
    #pragma unroll
    for (int nt = 0; nt < 4; ++nt) {
        accR[nt] = (f32x4){0.f, 0.f, 0.f, 0.f};
        accI[nt] = (f32x4){0.f, 0.f, 0.f, 0.f};
    }
    const us* pAr[2];
    const us* pAi[2];
    const us* pB[4][2];
    {
        size_t rr = (size_t)(bm + ln) * 512 + quad * 8;
        pAr[0] = Ah + rr;        pAr[1] = Al + rr;
        pAi[0] = Ah + N1_ + rr;  pAi[1] = Al + N1_ + rr;
    }
    #pragma unroll
    for (int nt = 0; nt < 4; ++nt) {
        size_t rr = (size_t)(bn + nt * 16 + ln) * 512 + quad * 8;
        pB[nt][0] = BTh + rr; pB[nt][1] = BTl + rr;
    }
    #pragma unroll 4
    for (int ks = 0; ks < 16; ++ks) {
        const int ko = ks * 32;
        short8 Ar[2], Ai[2], Bf[4][2];
        Ar[0] = *(const short8*)(pAr[0] + ko);
        Ar[1] = *(const short8*)(pAr[1] + ko);
        Ai[0] = *(const short8*)(pAi[0] + ko);
        Ai[1] = *(const short8*)(pAi[1] + ko);
        #pragma unroll
        for (int nt = 0; nt < 4; ++nt) {
            Bf[nt][0] = *(const short8*)(pB[nt][0] + ko);
            Bf[nt][1] = *(const short8*)(pB[nt][1] + ko);
        }
        #pragma unroll
        for (int nt = 0; nt < 4; ++nt) {
            accR[nt] = mfma16(Ar[0], Bf[nt][0], accR[nt]);
            accR[nt] = mfma16(Ar[0], Bf[nt][1], accR[nt]);
            accR[nt] = mfma16(Ar[1], Bf[nt][0], accR[nt]);
            accI[nt] = mfma16(Ai[0], Bf[nt][0], accI[nt]);
            accI[nt] = mfma16(Ai[0], Bf[nt][1], accI[nt]);
            accI[nt] = mfma16(Ai[1], Bf[nt][0], accI[nt]);
        }
    }
    // epilogue: gate in-register, write A2 bf16 h/l
    #pragma unroll
    for (int nt = 0; nt < 4; ++nt)
        #pragma unroll
        for (int r = 0; r < 4; ++r) {
            int m = bm + quad * 4 + r;
            int n = bn + nt * 16 + ln;
            size_t idx = (size_t)m * 512 + n;
            float gr = accR[nt][r], gi = accI[nt][r];
            float hr = bf2f(Ah[idx]) + bf2f(Al[idx]);
            float hi = bf2f(Ah[N1_ + idx]) + bf2f(Al[N1_ + idx]);
            float e = expf(-2.0f * gr);
            float sn, cs;
            sincosf(2.0f * gi, &sn, &cs);
            float dr = 1.0f + e * cs;
            float di = -e * sn;
            float nr = hr * gr - hi * gi;
            float ni = hr * gi + hi * gr;
            float inv = 1.0f / (dr * dr + di * di);
            float o2r = (nr * dr + ni * di) * inv;
            float o2i = (ni * dr - nr * di) * inv;
            us t = f2bf(o2r);
            A2h[idx] = t; A2l[idx] = f2bf(o2r - bf2f(t));
            t = f2bf(o2i);
            A2h[N1_ + idx] = t; A2l[N1_ + idx] = f2bf(o2i - bf2f(t));
        }
}

// ---------------- split-bf16 MFMA GEMM: C[8192,512] = A * W (WT given) -----
// R19: M-tile halved 128->64, grid.x doubled 64->128 (1024 blocks = 4/CU
// = 4 waves/SIMD; was 2/CU — latency-exposed K-loop).
__global__ __launch_bounds__(256) void gemm_mfma_kernel(
    const us* __restrict__ Ah, const us* __restrict__ Al,
    const us* __restrict__ BTh, const us* __restrict__ BTl,
    float* __restrict__ Cout, int mode)
{
    const int tid = threadIdx.x;
    const int w = tid >> 6, lane = tid & 63;
    const int ln = lane & 15, quad = lane >> 4;
    const int bm = blockIdx.x * 64 + w * 16;
    const int bn = blockIdx.y * 64;
    f32x4 acc[4];
    #pragma unroll
    for (int nt = 0; nt < 4; ++nt) acc[nt] = (f32x4){0.f, 0.f, 0.f, 0.f};
    const us* pA[2];
    const us* pB[4][2];
    {
        size_t r = (size_t)(bm + ln) * 512 + quad * 8;
        pA[0] = Ah + r; pA[1] = Al + r;
    }
    #pragma unroll
    for (int nt = 0; nt < 4; ++nt) {
        size_t r = (size_t)(bn + nt * 16 + ln) * 512 + quad * 8;
        pB[nt][0] = BTh + r; pB[nt][1] = BTl + r;
    }
    #pragma unroll
    for (int ks = 0; ks < 16; ++ks) {
        const int ko = ks * 32;
        short8 Af[2], Bf[4][2];
        Af[0] = *(const short8*)(pA[0] + ko);
        Af[1] = *(const short8*)(pA[1] + ko);
        #pragma unroll
        for (int nt = 0; nt < 4; ++nt) {
            Bf[nt][0] = *(const short8*)(pB[nt][0] + ko);
            Bf[nt][1] = *(const short8*)(pB[nt][1] + ko);
        }
        #pragma unroll
        for (int nt = 0; nt < 4; ++nt) {
            acc[nt] = mfma16(Af[0], Bf[nt][0], acc[nt]);
            acc[nt] = mfma16(Af[0], Bf[nt][1], acc[nt]);
            acc[nt] = mfma16(Af[1], Bf[nt][0], acc[nt]);
        }
    }
    #pragma unroll
    for (int nt = 0; nt < 4; ++nt)
        #pragma unroll
        for (int r = 0; r < 4; ++r) {
            int m = bm + quad * 4 + r;
            int n = bn + nt * 16 + ln;
            float v = acc[nt][r];
            if (mode == 0) {
                Cout[(size_t)m * 512 + n] = v;
            } else if (mode == 1) {
                if (m < 4096) Cout[2 * ((size_t)m * 512 + n)] = v;
                else          Cout[2 * ((size_t)(m - 4096) * 512 + n) + 1] = v;
            } else {
                if (m < 4096) Cout[(size_t)m * 512 + n] = v;
            }
        }
}

extern "C" void kernel_launch(void* const* d_in, const int* in_sizes, int n_in,
                              void* d_out, int out_size, void* d_ws, size_t ws_size,
                              hipStream_t stream)
{
    const float* x     = (const float*)d_in[0];
    const float* WQ    = (const float*)d_in[1];
    const float* WK    = (const float*)d_in[2];
    const float* WV    = (const float*)d_in[3];
    const float* theta = (const float*)d_in[4];
    const float* gamma = (const float*)d_in[5];
    const float* qk    = (const float*)d_in[7];
    const float* WO    = (const float*)d_in[8];
    const float* WG    = (const float*)d_in[9];
    float* out = (float*)d_out;

    const size_t N1 = (size_t)B_ * H_ * C_ * HW_;       // 2,097,152
    const size_t SQ = (size_t)B_ * H_ * C_ * 128;       // 4,194,304 shorts
    const size_t SV = (size_t)B_ * H_ * HW_ * C_;       // 2,097,152 shorts
    us* usw = (us*)d_ws;
    us *Qch = usw,            *Qcl = usw + SQ,
       *K1h = usw + 2 * SQ,   *K1l = usw + 3 * SQ,
       *VTh = usw + 4 * SQ,   *VTl = usw + 4 * SQ + SV; // shorts end at 5*N1 floats
    float* fw = (float*)d_ws;
    us *A1h = (us*)(fw + 5 * N1), *A1l = (us*)(fw + 6 * N1);
    // WT overlays dead K1 (wcvt blocks run after retention):
    us *WTGh = K1h,            *WTGl = K1h + 262144,
       *WTOh = K1h + 524288,  *WTOl = K1h + 786432;
    us *A2h = (us*)(fw + 9 * N1), *A2l = (us*)(fw + 10 * N1);
    // Pbuf = 3*N1 floats (768 x 8192) spans [7N1,10N1): dead before
    // gemm_gate writes A2 (9N1..11N1) — reduce consumed it already.
    float *Pbuf = fw + 7 * N1;

    proj_kernel<<<dim3(C_ / 32, B_ * H_), 256, 0, stream>>>(
        x, WQ, WK, WV, theta, Qch, Qcl, K1h, K1l, VTh, VTl);
    retention_kernel<<<dim3(768), 256, 0, stream>>>(
        Qch, Qcl, K1h, K1l, VTh, VTl, Pbuf, gamma, qk);
    reduce_wcvt_kernel<<<dim3(64, 16), 256, 0, stream>>>(
        Pbuf, A1h, A1l, WG, WO, WTGh, WTGl, WTOh, WTOl);

    gemm_gate_kernel<<<dim3(64, 8), 256, 0, stream>>>(
        A1h, A1l, WTGh, WTGl, A2h, A2l);

    int outmode = (out_size >= (int)(2 * N1)) ? 1 : 2;
    gemm_mfma_kernel<<<dim3(128, 8), 256, 0, stream>>>(
        A2h, A2l, WTOh, WTOl, out, outmode);
}

// Round 11
// 289.158 us; speedup vs baseline: 1.1826x; 1.1011x over previous
//
#include <hip/hip_runtime.h>
#include <cstdint>
#include <cstddef>

#define B_  2
#define H_  8
#define C_  2048
#define HW_ 64
#define HD_ 512   // H_*HW_
#define N1_ 2097152  // B_*H_*C_*HW_

typedef __attribute__((ext_vector_type(8))) short short8;
typedef __attribute__((ext_vector_type(4))) short short4v;
typedef __attribute__((ext_vector_type(4))) float f32x4;
typedef __attribute__((ext_vector_type(4))) int   int4v;
typedef unsigned short us;

static __device__ inline us f2bf(float f) {           // RNE
    unsigned u = __builtin_bit_cast(unsigned, f);
    u = u + 0x7FFFu + ((u >> 16) & 1u);
    return (us)(u >> 16);
}
static __device__ inline us f2bf_t(float f) {         // truncate (hot path)
    return (us)(__builtin_bit_cast(unsigned, f) >> 16);
}
static __device__ inline float bf2f(us s) {
    unsigned u = ((unsigned)s) << 16;
    return __builtin_bit_cast(float, u);
}
static __device__ inline f32x4 mfma16(short8 a, short8 b, f32x4 c) {
    return __builtin_amdgcn_mfma_f32_16x16x32_bf16(a, b, c, 0, 0, 0);
}
static __device__ inline short8 negbf(short8 v) {
    int4v u = __builtin_bit_cast(int4v, v);
    u ^= (int)0x80008000;
    return __builtin_bit_cast(short8, u);
}
// b64-pair LDS fragment load (rows padded -> 8B-aligned only)
static __device__ inline short8 lds_frag(const us* p) {
    short4v a = *(const short4v*)p;
    short4v b = *(const short4v*)(p + 4);
    return __builtin_shufflevector(a, b, 0, 1, 2, 3, 4, 5, 6, 7);
}
// V fragment read for permuted PV contraction (R16-verified): 8B at +0, +16
static __device__ inline short8 lds_fragg(const us* p) {
    short4v a = *(const short4v*)p;
    short4v b = *(const short4v*)(p + 16);
    return __builtin_shufflevector(a, b, 0, 1, 2, 3, 4, 5, 6, 7);
}
// pack two f32 into bf16x2 high word + bf16x2 residual word (R16-verified)
static __device__ inline void pkhl(float a, float b, unsigned &hw, unsigned &lw) {
    us ha = f2bf_t(a), hb = f2bf_t(b);
    hw = (unsigned)ha | ((unsigned)hb << 16);
    float la = a - bf2f(ha), lb = b - bf2f(hb);
    lw = (unsigned)f2bf_t(la) | ((unsigned)f2bf_t(lb) << 16);
}
static __device__ inline short8 bcs8(unsigned a, unsigned b, unsigned c, unsigned d) {
    int4v v = {(int)a, (int)b, (int)c, (int)d};
    return __builtin_bit_cast(short8, v);
}

// ---------------- Projection + rotary phase ----------------
__global__ __launch_bounds__(256) void proj_kernel(
    const float* __restrict__ x, const float* __restrict__ WQ,
    const float* __restrict__ WK, const float* __restrict__ WV,
    const float* __restrict__ theta,
    us* __restrict__ Qch, us* __restrict__ Qcl,
    us* __restrict__ K1h, us* __restrict__ K1l,
    us* __restrict__ VTh, us* __restrict__ VTl)
{
    __shared__ float smem[3 * 64 * 68 + 32 * 68];   // 60,928 B
    float* sWT = smem;               // [3][64 j][68 i]
    float* sx  = smem + 3 * 64 * 68; // [32 c][68 i]
    int tid = threadIdx.x;
    int bh = blockIdx.y; int h = bh & 7;
    int c0 = blockIdx.x * 32;
    for (int t = tid; t < 1024; t += 256) {
        int j4 = (t & 15) * 4, i = t >> 4;
        float4 wq = *(const float4*)&WQ[(h * 64 + i) * 64 + j4];
        float4 wk = *(const float4*)&WK[(h * 64 + i) * 64 + j4];
        float4 wv = *(const float4*)&WV[(h * 64 + i) * 64 + j4];
        sWT[(j4 + 0) * 68 + i] = wq.x; sWT[(j4 + 1) * 68 + i] = wq.y;
        sWT[(j4 + 2) * 68 + i] = wq.z; sWT[(j4 + 3) * 68 + i] = wq.w;
        sWT[64 * 68 + (j4 + 0) * 68 + i] = wk.x; sWT[64 * 68 + (j4 + 1) * 68 + i] = wk.y;
        sWT[64 * 68 + (j4 + 2) * 68 + i] = wk.z; sWT[64 * 68 + (j4 + 3) * 68 + i] = wk.w;
        sWT[2 * 64 * 68 + (j4 + 0) * 68 + i] = wv.x; sWT[2 * 64 * 68 + (j4 + 1) * 68 + i] = wv.y;
        sWT[2 * 64 * 68 + (j4 + 2) * 68 + i] = wv.z; sWT[2 * 64 * 68 + (j4 + 3) * 68 + i] = wv.w;
    }
    for (int t = tid; t < 512; t += 256) {
        int i4 = (t & 15) * 4, c = t >> 4;
        *(float4*)&sx[c * 68 + i4] =
            *(const float4*)&x[((size_t)((bh >> 3) * C_ + c0 + c)) * HD_ + h * 64 + i4];
    }
    __syncthreads();
    int j = tid & 63, cg = tid >> 6;     // cg uniform per wave
    float aq[8] = {}, ak[8] = {}, av[8] = {};
    const float* pw0 = &sWT[j * 68];
    const float* pw1 = &sWT[64 * 68 + j * 68];
    const float* pw2 = &sWT[2 * 64 * 68 + j * 68];
    const float* px  = &sx[cg * 8 * 68];
    #pragma unroll 2
    for (int i0 = 0; i0 < 64; i0 += 4) {
        float4 w0 = *(const float4*)(pw0 + i0);
        float4 w1 = *(const float4*)(pw1 + i0);
        float4 w2 = *(const float4*)(pw2 + i0);
        #pragma unroll
        for (int cc = 0; cc < 8; ++cc) {
            float4 xv = *(const float4*)(px + cc * 68 + i0);
            aq[cc] += xv.x * w0.x + xv.y * w0.y + xv.z * w0.z + xv.w * w0.w;
            ak[cc] += xv.x * w1.x + xv.y * w1.y + xv.z * w1.z + xv.w * w1.w;
            av[cc] += xv.x * w2.x + xv.y * w2.y + xv.z * w2.z + xv.w * w2.w;
        }
    }
    float th = theta[h * 64 + j];
    #pragma unroll
    for (int cc = 0; cc < 8; ++cc) {
        int c = c0 + cg * 8 + cc;
        float sn, cs;
        sincosf((float)c * th, &sn, &cs);
        float qr = aq[cc] * cs, qi = aq[cc] * sn;
        float kr = ak[cc] * cs, nki = ak[cc] * sn;   // nki = -Ki
        size_t rq = ((size_t)bh * C_ + c) * 128;
        us h0;
        h0 = f2bf(qr);  Qch[rq + j]      = h0; Qcl[rq + j]      = f2bf(qr  - bf2f(h0));
        h0 = f2bf(qi);  Qch[rq + 64 + j] = h0; Qcl[rq + 64 + j] = f2bf(qi  - bf2f(h0));
        h0 = f2bf(kr);  K1h[rq + j]      = h0; K1l[rq + j]      = f2bf(kr  - bf2f(h0));
        h0 = f2bf(nki); K1h[rq + 64 + j] = h0; K1l[rq + 64 + j] = f2bf(nki - bf2f(h0));
    }
    __syncthreads();
    float* T0 = smem;                   // [64][33]
    #pragma unroll
    for (int cc = 0; cc < 8; ++cc)
        T0[j * 33 + cg * 8 + cc] = av[cc];
    __syncthreads();
    int cc2 = tid & 31, jg = tid >> 5;
    #pragma unroll
    for (int jj = 0; jj < 8; ++jj) {
        int jr = jg * 8 + jj;
        float v = T0[jr * 33 + cc2];
        us hh = f2bf(v);
        size_t o = ((size_t)bh * 64 + jr) * C_ + c0 + cc2;
        VTh[o] = hh;
        VTl[o] = f2bf(v - bf2f(hh));
    }
}

// ---------------- MFMA Retention (R17 VERBATIM — proven 98.5us) -----------
// R17: in-reg S (swapped QK, R16-verified) + cooperative K stage. 98.5us,
// MfmaUtil 34.5%. R18's prefetch-across-barrier SPILLED (WRITE +194MB
// scratch, 139us) — twice-falsified (R16, R18); do not reintroduce.
__global__ __launch_bounds__(256, 3) void retention_kernel(
    const us* __restrict__ Qch, const us* __restrict__ Qcl,
    const us* __restrict__ K1h, const us* __restrict__ K1l,
    const us* __restrict__ VTh, const us* __restrict__ VTl,
    float* __restrict__ Pbuf,
    const float* __restrict__ gamma, const float* __restrict__ qk_scale)
{
    constexpr int SPV = 68;            // V row pad (shorts)
    constexpr int SPK = 132;           // K row pad (shorts), 8B-aligned rows
    constexpr int PLV = 64 * SPV;      // 4352 shorts
    constexpr int PLK = 64 * SPK;      // 8448 shorts
    __shared__ us smem[2 * PLK + 2 * PLV];   // 51,200 B
    us* sKh = smem;
    us* sKl = smem + PLK;
    us* sVh = smem + 2 * PLK;
    us* sVl = smem + 2 * PLK + PLV;

    const int tid = threadIdx.x;
    const int w = tid >> 6, lane = tid & 63;
    const int ln = lane & 15, quad = lane >> 4;
    const int r = (int)blockIdx.x >> 4, bh = (int)blockIdx.x & 15;
    const int h = bh & 7;
    int qt, klo, slot;
    if (r == 0)       { qt = 15; klo = 0;  slot = 15; }
    else if (r == 1)  { qt = 31; klo = 16; slot = 47; }
    else if (r <= 17) { qt = 14 + r; klo = 0; slot = 16 + 2 * (qt - 16); }
    else {
        int u = r - 18, s = 15 - (u >> 1);
        if ((u & 1) == 0) { qt = s - 1;  klo = 0;  slot = qt; }
        else              { qt = 15 + s; klo = 16; slot = 17 + 2 * (qt - 16); }
    }
    const int khi = (qt >= 16 && klo == 0) ? 15 : qt;
    const int qc0 = qt * 64;
    const float lg = log2f(gamma[h]);
    const float inv_scale = 1.0f / qk_scale[0];
    const int qloc = w * 16 + ln;                    // this lane's q (tile-local)
    const float rowl = exp2f(lg * (float)qloc);
    const float e16  = exp2f(-16.0f * lg);
    float colq[4];
    #pragma unroll
    for (int r2 = 0; r2 < 4; ++r2)
        colq[r2] = exp2f(-lg * (float)(quad * 4 + r2));

    short8 Qh[4], Ql[4];
    {
        size_t qrow = ((size_t)bh * C_ + qc0 + w * 16 + ln) * 128;
        #pragma unroll
        for (int ck = 0; ck < 4; ++ck) {
            size_t off = qrow + ck * 32 + quad * 8;
            Qh[ck] = *(const short8*)(Qch + off);
            Ql[ck] = *(const short8*)(Qcl + off);
        }
    }
    f32x4 zz = {0.0f, 0.0f, 0.0f, 0.0f};
    f32x4 Or[4], Oi[4];
    #pragma unroll
    for (int it = 0; it < 4; ++it) { Or[it] = zz; Oi[it] = zz; }

    const size_t vtb = (size_t)bh * 64 * C_;
    const int krow_s = tid >> 2, kseg = (tid & 3) * 32;   // K stage coords
    const int vi = tid >> 2, vseg = (tid & 3) * 16;       // V stage coords

    for (int kt = klo; kt <= khi; ++kt) {
        const int kc0 = kt * 64;
        __syncthreads();   // all waves done reading sK/sV of kt-1
        {   // ---- cooperative stage: K (once per block!) + V, all loads together
            const size_t kb = ((size_t)bh * C_ + kc0 + krow_s) * 128 + kseg;
            const us* gh = K1h + kb;
            const us* gl = K1l + kb;
            us* dkh = &sKh[krow_s * SPK + kseg];
            us* dkl = &sKl[krow_s * SPK + kseg];
            #pragma unroll
            for (int m = 0; m < 4; ++m) {
                short8 a = *(const short8*)(gh + m * 8);
                *(short4v*)(dkh + m * 8)     = __builtin_shufflevector(a, a, 0, 1, 2, 3);
                *(short4v*)(dkh + m * 8 + 4) = __builtin_shufflevector(a, a, 4, 5, 6, 7);
                a = *(const short8*)(gl + m * 8);
                *(short4v*)(dkl + m * 8)     = __builtin_shufflevector(a, a, 0, 1, 2, 3);
                *(short4v*)(dkl + m * 8 + 4) = __builtin_shufflevector(a, a, 4, 5, 6, 7);
            }
            size_t g = vtb + (size_t)vi * C_ + kc0 + vseg;
            short8 a = *(const short8*)(VTh + g);
            short8 bq = *(const short8*)(VTh + g + 8);
            *(short4v*)&sVh[vi * SPV + vseg]      = __builtin_shufflevector(a, a, 0, 1, 2, 3);
            *(short4v*)&sVh[vi * SPV + vseg + 4]  = __builtin_shufflevector(a, a, 4, 5, 6, 7);
            *(short4v*)&sVh[vi * SPV + vseg + 8]  = __builtin_shufflevector(bq, bq, 0, 1, 2, 3);
            *(short4v*)&sVh[vi * SPV + vseg + 12] = __builtin_shufflevector(bq, bq, 4, 5, 6, 7);
            a  = *(const short8*)(VTl + g);
            bq = *(const short8*)(VTl + g + 8);
            *(short4v*)&sVl[vi * SPV + vseg]      = __builtin_shufflevector(a, a, 0, 1, 2, 3);
            *(short4v*)&sVl[vi * SPV + vseg + 4]  = __builtin_shufflevector(a, a, 4, 5, 6, 7);
            *(short4v*)&sVl[vi * SPV + vseg + 8]  = __builtin_shufflevector(bq, bq, 0, 1, 2, 3);
            *(short4v*)&sVl[vi * SPV + vseg + 12] = __builtin_shufflevector(bq, bq, 4, 5, 6, 7);
        }
        __syncthreads();   // staged tile ready; no further barrier this kt
        const float tf = exp2f(lg * (float)(qc0 - kc0)) * inv_scale;
        const bool diag = (kt == qt);
        float snt = tf * rowl;
        #pragma unroll
        for (int half = 0; half < 2; ++half) {
            unsigned WRH[2][2], WRL[2][2], WIH[2][2], WIL[2][2];
            #pragma unroll
            for (int n2 = 0; n2 < 2; ++n2) {
                const int nt = half * 2 + n2;
                const int kr = (nt * 16 + ln) * SPK;
                short8 Kh[4], Kl[4];
                #pragma unroll
                for (int ck = 0; ck < 4; ++ck) {
                    Kh[ck] = lds_frag(&sKh[kr + ck * 32 + quad * 8]);
                    Kl[ck] = lds_frag(&sKl[kr + ck * 32 + quad * 8]);
                }
                // swapped QK (R16-verified): S^T = K·Q
                f32x4 sr = zz, si = zz;
                #pragma unroll
                for (int ck = 0; ck < 4; ++ck) {
                    sr = mfma16(Kh[ck], Qh[ck], sr);
                    sr = mfma16(Kl[ck], Qh[ck], sr);
                    sr = mfma16(Kh[ck], Ql[ck], sr);
                }
                short8 nKh2 = negbf(Kh[2]), nKh3 = negbf(Kh[3]);
                short8 nKl2 = negbf(Kl[2]), nKl3 = negbf(Kl[3]);
                si = mfma16(nKh2, Qh[0], si); si = mfma16(nKl2, Qh[0], si); si = mfma16(nKh2, Ql[0], si);
                si = mfma16(nKh3, Qh[1], si); si = mfma16(nKl3, Qh[1], si); si = mfma16(nKh3, Ql[1], si);
                si = mfma16(Kh[0], Qh[2], si); si = mfma16(Kl[0], Qh[2], si); si = mfma16(Kh[0], Ql[2], si);
                si = mfma16(Kh[1], Qh[3], si); si = mfma16(Kl[1], Qh[3], si); si = mfma16(Kh[1], Ql[3], si);
                // decay weight + causal mask in transposed layout (R16-verified):
                // lane holds S[qloc][k = nt*16 + quad*4 + r2]
                float ar[4], ai[4];
                #pragma unroll
                for (int r2 = 0; r2 < 4; ++r2) {
                    float wv = snt * colq[r2];
                    if (diag && (qloc < nt * 16 + quad * 4 + r2)) wv = 0.0f;
                    ar[r2] = sr[r2] * wv;
                    ai[r2] = si[r2] * wv;
                }
                pkhl(ar[0], ar[1], WRH[n2][0], WRL[n2][0]);
                pkhl(ar[2], ar[3], WRH[n2][1], WRL[n2][1]);
                pkhl(ai[0], ai[1], WIH[n2][0], WIL[n2][0]);
                pkhl(ai[2], ai[3], WIH[n2][1], WIL[n2][1]);
                snt *= e16;
            }
            // PV A-frags in-register; V read permuted to match (R16-verified)
            short8 SRH = bcs8(WRH[0][0], WRH[0][1], WRH[1][0], WRH[1][1]);
            short8 SRL = bcs8(WRL[0][0], WRL[0][1], WRL[1][0], WRL[1][1]);
            short8 SIH = bcs8(WIH[0][0], WIH[0][1], WIH[1][0], WIH[1][1]);
            short8 SIL = bcs8(WIL[0][0], WIL[0][1], WIL[1][0], WIL[1][1]);
            #pragma unroll
            for (int it = 0; it < 4; ++it) {
                int vb = (it * 16 + ln) * SPV + half * 32 + quad * 4;
                short8 Vh = lds_fragg(&sVh[vb]);
                short8 Vl = lds_fragg(&sVl[vb]);
                Or[it] = mfma16(SRH, Vh, Or[it]);
                Or[it] = mfma16(SRH, Vl, Or[it]);
                Or[it] = mfma16(SRL, Vh, Or[it]);
                Oi[it] = mfma16(SIH, Vh, Oi[it]);
                Oi[it] = mfma16(SIH, Vl, Oi[it]);
                Oi[it] = mfma16(SIL, Vh, Oi[it]);
            }
        }
    }
    float* Pr = Pbuf + ((size_t)(bh * 48 + slot)) * 8192;
    float* Pi = Pr + 4096;
    #pragma unroll
    for (int it = 0; it < 4; ++it) {
        #pragma unroll
        for (int rr2 = 0; rr2 < 4; ++rr2) {
            int qL = w * 16 + quad * 4 + rr2, iX = it * 16 + ln;
            Pr[qL * 64 + iX] = Or[it][rr2];
            Pi[qL * 64 + iX] = Oi[it][rr2];
        }
    }
}

// -------- Merged: partial reduce + L2 norm -> A1   AND   weight cvt --------
// grid (64, 16): bx<32 -> reduce (qt=bx, bh=by); bx>=32 -> wcvt tile.
__global__ __launch_bounds__(256) void reduce_wcvt_kernel(
    const float* __restrict__ Pbuf,
    us* __restrict__ A1h, us* __restrict__ A1l,
    const float* __restrict__ WG, const float* __restrict__ WO,
    us* __restrict__ Gh, us* __restrict__ Gl,
    us* __restrict__ Oh, us* __restrict__ Ol)
{
    __shared__ float T[32 * 33];
    if ((int)blockIdx.x < 32) {
        const int qt = blockIdx.x, bh = blockIdx.y;
        const int h = bh & 7, b = bh >> 3;
        const int t = threadIdx.x;
        const int q = t >> 2, i0 = (t & 3) * 16;
        const int slot0 = (qt < 16) ? qt : 16 + 2 * (qt - 16);
        const int nparts = (qt < 16) ? 1 : 2;
        const float* P0 = Pbuf + ((size_t)(bh * 48 + slot0)) * 8192 + q * 64 + i0;
        float orv[16], oiv[16];
        #pragma unroll
        for (int s4 = 0; s4 < 4; ++s4) {
            *(float4*)&orv[s4 * 4] = *(const float4*)(P0 + s4 * 4);
            *(float4*)&oiv[s4 * 4] = *(const float4*)(P0 + 4096 + s4 * 4);
        }
        if (nparts == 2) {
            const float* P1 = P0 + 8192;
            #pragma unroll
            for (int s4 = 0; s4 < 4; ++s4) {
                float4 a = *(const float4*)(P1 + s4 * 4);
                float4 c = *(const float4*)(P1 + 4096 + s4 * 4);
                orv[s4 * 4]     += a.x; orv[s4 * 4 + 1] += a.y;
                orv[s4 * 4 + 2] += a.z; orv[s4 * 4 + 3] += a.w;
                oiv[s4 * 4]     += c.x; oiv[s4 * 4 + 1] += c.y;
                oiv[s4 * 4 + 2] += c.z; oiv[s4 * 4 + 3] += c.w;
            }
        }
        float ss = 0.0f;
        #pragma unroll
        for (int k = 0; k < 16; ++k) ss += orv[k] * orv[k] + oiv[k] * oiv[k];
        ss += __shfl_xor(ss, 1);
        ss += __shfl_xor(ss, 2);
        float rn = rsqrtf(ss);
        size_t o = (((size_t)(b * C_ + qt * 64 + q)) * H_ + h) * HW_ + i0;
        us th[16], tl[16];
        #pragma unroll
        for (int k = 0; k < 16; ++k) {
            float v = orv[k] * rn;
            us hh = f2bf(v); th[k] = hh; tl[k] = f2bf(v - bf2f(hh));
        }
        *(short8*)&A1h[o] = *(short8*)&th[0]; *(short8*)&A1h[o + 8] = *(short8*)&th[8];
        *(short8*)&A1l[o] = *(short8*)&tl[0]; *(short8*)&A1l[o + 8] = *(short8*)&tl[8];
        #pragma unroll
        for (int k = 0; k < 16; ++k) {
            float v = oiv[k] * rn;
            us hh = f2bf(v); th[k] = hh; tl[k] = f2bf(v - bf2f(hh));
        }
        *(short8*)&A1h[N1_ + o] = *(short8*)&th[0]; *(short8*)&A1h[N1_ + o + 8] = *(short8*)&th[8];
        *(short8*)&A1l[N1_ + o] = *(short8*)&tl[0]; *(short8*)&A1l[N1_ + o + 8] = *(short8*)&tl[8];
    } else {
        int widx = ((int)blockIdx.x - 32) * 16 + (int)blockIdx.y;  // 0..511
        int z = widx >> 8, w2 = widx & 255;
        const float* src = z ? WO : WG;
        us* dh = z ? Oh : Gh;
        us* dl = z ? Ol : Gl;
        int k0 = (w2 >> 4) * 32, n0 = (w2 & 15) * 32;
        int c = threadIdx.x & 31, r8 = threadIdx.x >> 5;
        #pragma unroll
        for (int rr = 0; rr < 4; ++rr) {
            int rw = r8 * 4 + rr;
            T[rw * 33 + c] = src[(size_t)(k0 + rw) * 512 + n0 + c];
        }
        __syncthreads();
        #pragma unroll
        for (int rr = 0; rr < 4; ++rr) {
            int rw = r8 * 4 + rr;           // n-local
            float v = T[c * 33 + rw];       // [k-local=c][n-local=rw]
            us hh = f2bf(v);
            size_t o = (size_t)(n0 + rw) * 512 + k0 + c;
            dh[o] = hh; dl[o] = f2bf(v - bf2f(hh));
        }
    }
}

// ------- Fused G-GEMM + complex gate: A2 = gate(A1, A1*WG) -----------------
// R20: R17's 128-row tile (R19's 64-row halving REGRESSED: B traffic x2) +
// cooperative B staging. R17's pB[] didn't depend on w — all 4 waves
// redundantly streamed the same 128KB B panel (same pathology R17 fixed in
// retention, -38% there). Now: K in 4 chunks of 128; per chunk all 256
// threads stage B[64][128] h+l into LDS (33,792 B) at one latency point.
__global__ __launch_bounds__(256) void gemm_gate_kernel(
    const us* __restrict__ Ah, const us* __restrict__ Al,
    const us* __restrict__ BTh, const us* __restrict__ BTl,
    us* __restrict__ A2h, us* __restrict__ A2l)
{
    constexpr int SPB = 132;            // B row pad (shorts)
    constexpr int PLB = 64 * SPB;       // 8448 shorts
    __shared__ us sB[2 * PLB];          // 33,792 B
    us* sBh = sB;
    us* sBl = sB + PLB;
    const int tid = threadIdx.x;
    const int w = tid >> 6, lane = tid & 63;
    const int ln = lane & 15, quad = lane >> 4;
    const int bm = blockIdx.x * 128 + w * 32;   // re-plane rows [0,4096)
    const int bn = blockIdx.y * 64;
    const int brow = tid >> 2, bseg = (tid & 3) * 32;  // B stage coords
    f32x4 accR[2][4], accI[2][4];
    #pragma unroll
    for (int mt = 0; mt < 2; ++mt)
        #pragma unroll
        for (int nt = 0; nt < 4; ++nt) {
            accR[mt][nt] = (f32x4){0.f, 0.f, 0.f, 0.f};
            accI[mt][nt] = (f32x4){0.f, 0.f, 0.f, 0.f};
        }
    const us* pAr[2][2];
    const us* pAi[2][2];
    #pragma unroll
    for (int mt = 0; mt < 2; ++mt) {
        size_t rr = (size_t)(bm + mt * 16 + ln) * 512 + quad * 8;
        pAr[mt][0] = Ah + rr;        pAr[mt][1] = Al + rr;
        pAi[mt][0] = Ah + N1_ + rr;  pAi[mt][1] = Al + N1_ + rr;
    }
    for (int kc = 0; kc < 4; ++kc) {
        const int kc0 = kc * 128;
        __syncthreads();
        {   // cooperative B stage: row brow, shorts [bseg, bseg+32) of chunk
            const size_t gb = (size_t)(bn + brow) * 512 + kc0 + bseg;
            us* dh = &sBh[brow * SPB + bseg];
            us* dl = &sBl[brow * SPB + bseg];
            #pragma unroll
            for (int m = 0; m < 4; ++m) {
                short8 a = *(const short8*)(BTh + gb + m * 8);
                *(short4v*)(dh + m * 8)     = __builtin_shufflevector(a, a, 0, 1, 2, 3);
                *(short4v*)(dh + m * 8 + 4) = __builtin_shufflevector(a, a, 4, 5, 6, 7);
                a = *(const short8*)(BTl + gb + m * 8);
                *(short4v*)(dl + m * 8)     = __builtin_shufflevector(a, a, 0, 1, 2, 3);
                *(short4v*)(dl + m * 8 + 4) = __builtin_shufflevector(a, a, 4, 5, 6, 7);
            }
        }
        __syncthreads();
        #pragma unroll
        for (int ks = 0; ks < 4; ++ks) {
            const int ko = kc0 + ks * 32;
            const int lo = ks * 32 + quad * 8;
            short8 Ar[2][2], Ai[2][2], Bf[4][2];
            #pragma unroll
            for (int mt = 0; mt < 2; ++mt) {
                Ar[mt][0] = *(const short8*)(pAr[mt][0] + ko);
                Ar[mt][1] = *(const short8*)(pAr[mt][1] + ko);
                Ai[mt][0] = *(const short8*)(pAi[mt][0] + ko);
                Ai[mt][1] = *(const short8*)(pAi[mt][1] + ko);
            }
            #pragma unroll
            for (int nt = 0; nt < 4; ++nt) {
                Bf[nt][0] = lds_frag(&sBh[(nt * 16 + ln) * SPB + lo]);
                Bf[nt][1] = lds_frag(&sBl[(nt * 16 + ln) * SPB + lo]);
            }
            #pragma unroll
            for (int mt = 0; mt < 2; ++mt)
                #pragma unroll
                for (int nt = 0; nt < 4; ++nt) {
                    accR[mt][nt] = mfma16(Ar[mt][0], Bf[nt][0], accR[mt][nt]);
                    accR[mt][nt] = mfma16(Ar[mt][0], Bf[nt][1], accR[mt][nt]);
                    accR[mt][nt] = mfma16(Ar[mt][1], Bf[nt][0], accR[mt][nt]);
                    accI[mt][nt] = mfma16(Ai[mt][0], Bf[nt][0], accI[mt][nt]);
                    accI[mt][nt] = mfma16(Ai[mt][0], Bf[nt][1], accI[mt][nt]);
                    accI[mt][nt] = mfma16(Ai[mt][1], Bf[nt][0], accI[mt][nt]);
                }
        }
    }
    // epilogue: gate in-register, write A2 bf16 h/l (R17 verbatim)
    #pragma unroll
    for (int mt = 0; mt < 2; ++mt)
        #pragma unroll
        for (int nt = 0; nt < 4; ++nt)
            #pragma unroll
            for (int r = 0; r < 4; ++r) {
                int m = bm + mt * 16 + quad * 4 + r;
                int n = bn + nt * 16 + ln;
                size_t idx = (size_t)m * 512 + n;
                float gr = accR[mt][nt][r], gi = accI[mt][nt][r];
                float hr = bf2f(Ah[idx]) + bf2f(Al[idx]);
                float hi = bf2f(Ah[N1_ + idx]) + bf2f(Al[N1_ + idx]);
                float e = expf(-2.0f * gr);
                float sn, cs;
                sincosf(2.0f * gi, &sn, &cs);
                float dr = 1.0f + e * cs;
                float di = -e * sn;
                float nr = hr * gr - hi * gi;
                float ni = hr * gi + hi * gr;
                float inv = 1.0f / (dr * dr + di * di);
                float o2r = (nr * dr + ni * di) * inv;
                float o2i = (ni * dr - nr * di) * inv;
                us t = f2bf(o2r);
                A2h[idx] = t; A2l[idx] = f2bf(o2r - bf2f(t));
                t = f2bf(o2i);
                A2h[N1_ + idx] = t; A2l[N1_ + idx] = f2bf(o2i - bf2f(t));
            }
}

// ---------------- split-bf16 MFMA GEMM: C[8192,512] = A * W (WT given) -----
// R20: R17's 128-row tile + cooperative B staging (see gemm_gate comment).
__global__ __launch_bounds__(256) void gemm_mfma_kernel(
    const us* __restrict__ Ah, const us* __restrict__ Al,
    const us* __restrict__ BTh, const us* __restrict__ BTl,
    float* __restrict__ Cout, int mode)
{
    constexpr int SPB = 132;
    constexpr int PLB = 64 * SPB;
    __shared__ us sB[2 * PLB];          // 33,792 B
    us* sBh = sB;
    us* sBl = sB + PLB;
    const int tid = threadIdx.x;
    const int w = tid >> 6, lane = tid & 63;
    const int ln = lane & 15, quad = lane >> 4;
    const int bm = blockIdx.x * 128 + w * 32;
    const int bn = blockIdx.y * 64;
    const int brow = tid >> 2, bseg = (tid & 3) * 32;
    f32x4 acc[2][4];
    #pragma unroll
    for (int mt = 0; mt < 2; ++mt)
        #pragma unroll
        for (int nt = 0; nt < 4; ++nt) acc[mt][nt] = (f32x4){0.f, 0.f, 0.f, 0.f};
    const us* pA[2][2];
    #pragma unroll
    for (int mt = 0; mt < 2; ++mt) {
        size_t r = (size_t)(bm + mt * 16 + ln) * 512 + quad * 8;
        pA[mt][0] = Ah + r; pA[mt][1] = Al + r;
    }
    for (int kc = 0; kc < 4; ++kc) {
        const int kc0 = kc * 128;
        __syncthreads();
        {
            const size_t gb = (size_t)(bn + brow) * 512 + kc0 + bseg;
            us* dh = &sBh[brow * SPB + bseg];
            us* dl = &sBl[brow * SPB + bseg];
            #pragma unroll
            for (int m = 0; m < 4; ++m) {
                short8 a = *(const short8*)(BTh + gb + m * 8);
                *(short4v*)(dh + m * 8)     = __builtin_shufflevector(a, a, 0, 1, 2, 3);
                *(short4v*)(dh + m * 8 + 4) = __builtin_shufflevector(a, a, 4, 5, 6, 7);
                a = *(const short8*)(BTl + gb + m * 8);
                *(short4v*)(dl + m * 8)     = __builtin_shufflevector(a, a, 0, 1, 2, 3);
                *(short4v*)(dl + m * 8 + 4) = __builtin_shufflevector(a, a, 4, 5, 6, 7);
            }
        }
        __syncthreads();
        #pragma unroll
        for (int ks = 0; ks < 4; ++ks) {
            const int ko = kc0 + ks * 32;
            const int lo = ks * 32 + quad * 8;
            short8 Af[2][2], Bf[4][2];
            #pragma unroll
            for (int mt = 0; mt < 2; ++mt) {
                Af[mt][0] = *(const short8*)(pA[mt][0] + ko);
                Af[mt][1] = *(const short8*)(pA[mt][1] + ko);
            }
            #pragma unroll
            for (int nt = 0; nt < 4; ++nt) {
                Bf[nt][0] = lds_frag(&sBh[(nt * 16 + ln) * SPB + lo]);
                Bf[nt][1] = lds_frag(&sBl[(nt * 16 + ln) * SPB + lo]);
            }
            #pragma unroll
            for (int mt = 0; mt < 2; ++mt)
                #pragma unroll
                for (int nt = 0; nt < 4; ++nt) {
                    acc[mt][nt] = mfma16(Af[mt][0], Bf[nt][0], acc[mt][nt]);
                    acc[mt][nt] = mfma16(Af[mt][0], Bf[nt][1], acc[mt][nt]);
                    acc[mt][nt] = mfma16(Af[mt][1], Bf[nt][0], acc[mt][nt]);
                }
        }
    }
    #pragma unroll
    for (int mt = 0; mt < 2; ++mt)
        #pragma unroll
        for (int nt = 0; nt < 4; ++nt)
            #pragma unroll
            for (int r = 0; r < 4; ++r) {
                int m = bm + mt * 16 + quad * 4 + r;
                int n = bn + nt * 16 + ln;
                float v = acc[mt][nt][r];
                if (mode == 0) {
                    Cout[(size_t)m * 512 + n] = v;
                } else if (mode == 1) {
                    if (m < 4096) Cout[2 * ((size_t)m * 512 + n)] = v;
                    else          Cout[2 * ((size_t)(m - 4096) * 512 + n) + 1] = v;
                } else {
                    if (m < 4096) Cout[(size_t)m * 512 + n] = v;
                }
            }
}

extern "C" void kernel_launch(void* const* d_in, const int* in_sizes, int n_in,
                              void* d_out, int out_size, void* d_ws, size_t ws_size,
                              hipStream_t stream)
{
    const float* x     = (const float*)d_in[0];
    const float* WQ    = (const float*)d_in[1];
    const float* WK    = (const float*)d_in[2];
    const float* WV    = (const float*)d_in[3];
    const float* theta = (const float*)d_in[4];
    const float* gamma = (const float*)d_in[5];
    const float* qk    = (const float*)d_in[7];
    const float* WO    = (const float*)d_in[8];
    const float* WG    = (const float*)d_in[9];
    float* out = (float*)d_out;

    const size_t N1 = (size_t)B_ * H_ * C_ * HW_;       // 2,097,152
    const size_t SQ = (size_t)B_ * H_ * C_ * 128;       // 4,194,304 shorts
    const size_t SV = (size_t)B_ * H_ * HW_ * C_;       // 2,097,152 shorts
    us* usw = (us*)d_ws;
    us *Qch = usw,            *Qcl = usw + SQ,
       *K1h = usw + 2 * SQ,   *K1l = usw + 3 * SQ,
       *VTh = usw + 4 * SQ,   *VTl = usw + 4 * SQ + SV; // shorts end at 5*N1 floats
    float* fw = (float*)d_ws;
    us *A1h = (us*)(fw + 5 * N1), *A1l = (us*)(fw + 6 * N1);
    // WT overlays dead K1 (wcvt blocks run after retention):
    us *WTGh = K1h,            *WTGl = K1h + 262144,
       *WTOh = K1h + 524288,  *WTOl = K1h + 786432;
    us *A2h = (us*)(fw + 9 * N1), *A2l = (us*)(fw + 10 * N1);
    // Pbuf = 3*N1 floats (768 x 8192) spans [7N1,10N1): dead before
    // gemm_gate writes A2 (9N1..11N1) — reduce consumed it already.
    float *Pbuf = fw + 7 * N1;

    proj_kernel<<<dim3(C_ / 32, B_ * H_), 256, 0, stream>>>(
        x, WQ, WK, WV, theta, Qch, Qcl, K1h, K1l, VTh, VTl);
    retention_kernel<<<dim3(768), 256, 0, stream>>>(
        Qch, Qcl, K1h, K1l, VTh, VTl, Pbuf, gamma, qk);
    reduce_wcvt_kernel<<<dim3(64, 16), 256, 0, stream>>>(
        Pbuf, A1h, A1l, WG, WO, WTGh, WTGl, WTOh, WTOl);

    gemm_gate_kernel<<<dim3(32, 8), 256, 0, stream>>>(
        A1h, A1l, WTGh, WTGl, A2h, A2l);

    int outmode = (out_size >= (int)(2 * N1)) ? 1 : 2;
    gemm_mfma_kernel<<<dim3(64, 8), 256, 0, stream>>>(
        A2h, A2l, WTOh, WTOl, out, outmode);
}

// Round 12
// 252.441 us; speedup vs baseline: 1.3546x; 1.1454x over previous
//
#include <hip/hip_runtime.h>
#include <cstdint>
#include <cstddef>

#define B_  2
#define H_  8
#define C_  2048
#define HW_ 64
#define HD_ 512   // H_*HW_
#define N1_ 2097152  // B_*H_*C_*HW_

typedef __attribute__((ext_vector_type(8))) short short8;
typedef __attribute__((ext_vector_type(4))) short short4v;
typedef __attribute__((ext_vector_type(4))) float f32x4;
typedef __attribute__((ext_vector_type(4))) int   int4v;
typedef unsigned short us;

static __device__ inline us f2bf(float f) {           // RNE
    unsigned u = __builtin_bit_cast(unsigned, f);
    u = u + 0x7FFFu + ((u >> 16) & 1u);
    return (us)(u >> 16);
}
static __device__ inline us f2bf_t(float f) {         // truncate (hot path)
    return (us)(__builtin_bit_cast(unsigned, f) >> 16);
}
static __device__ inline float bf2f(us s) {
    unsigned u = ((unsigned)s) << 16;
    return __builtin_bit_cast(float, u);
}
static __device__ inline f32x4 mfma16(short8 a, short8 b, f32x4 c) {
    return __builtin_amdgcn_mfma_f32_16x16x32_bf16(a, b, c, 0, 0, 0);
}
static __device__ inline short8 negbf(short8 v) {
    int4v u = __builtin_bit_cast(int4v, v);
    u ^= (int)0x80008000;
    return __builtin_bit_cast(short8, u);
}
// b64-pair LDS fragment load (rows padded -> 8B-aligned only)
static __device__ inline short8 lds_frag(const us* p) {
    short4v a = *(const short4v*)p;
    short4v b = *(const short4v*)(p + 4);
    return __builtin_shufflevector(a, b, 0, 1, 2, 3, 4, 5, 6, 7);
}
// V fragment read for permuted PV contraction (R16-verified): 8B at +0, +16
static __device__ inline short8 lds_fragg(const us* p) {
    short4v a = *(const short4v*)p;
    short4v b = *(const short4v*)(p + 16);
    return __builtin_shufflevector(a, b, 0, 1, 2, 3, 4, 5, 6, 7);
}
// pack two f32 into bf16x2 high word + bf16x2 residual word (R16-verified)
static __device__ inline void pkhl(float a, float b, unsigned &hw, unsigned &lw) {
    us ha = f2bf_t(a), hb = f2bf_t(b);
    hw = (unsigned)ha | ((unsigned)hb << 16);
    float la = a - bf2f(ha), lb = b - bf2f(hb);
    lw = (unsigned)f2bf_t(la) | ((unsigned)f2bf_t(lb) << 16);
}
static __device__ inline short8 bcs8(unsigned a, unsigned b, unsigned c, unsigned d) {
    int4v v = {(int)a, (int)b, (int)c, (int)d};
    return __builtin_bit_cast(short8, v);
}

// ---------------- Projection + rotary phase ----------------
__global__ __launch_bounds__(256) void proj_kernel(
    const float* __restrict__ x, const float* __restrict__ WQ,
    const float* __restrict__ WK, const float* __restrict__ WV,
    const float* __restrict__ theta,
    us* __restrict__ Qch, us* __restrict__ Qcl,
    us* __restrict__ K1h, us* __restrict__ K1l,
    us* __restrict__ VTh, us* __restrict__ VTl)
{
    __shared__ float smem[3 * 64 * 68 + 32 * 68];   // 60,928 B
    float* sWT = smem;               // [3][64 j][68 i]
    float* sx  = smem + 3 * 64 * 68; // [32 c][68 i]
    int tid = threadIdx.x;
    int bh = blockIdx.y; int h = bh & 7;
    int c0 = blockIdx.x * 32;
    for (int t = tid; t < 1024; t += 256) {
        int j4 = (t & 15) * 4, i = t >> 4;
        float4 wq = *(const float4*)&WQ[(h * 64 + i) * 64 + j4];
        float4 wk = *(const float4*)&WK[(h * 64 + i) * 64 + j4];
        float4 wv = *(const float4*)&WV[(h * 64 + i) * 64 + j4];
        sWT[(j4 + 0) * 68 + i] = wq.x; sWT[(j4 + 1) * 68 + i] = wq.y;
        sWT[(j4 + 2) * 68 + i] = wq.z; sWT[(j4 + 3) * 68 + i] = wq.w;
        sWT[64 * 68 + (j4 + 0) * 68 + i] = wk.x; sWT[64 * 68 + (j4 + 1) * 68 + i] = wk.y;
        sWT[64 * 68 + (j4 + 2) * 68 + i] = wk.z; sWT[64 * 68 + (j4 + 3) * 68 + i] = wk.w;
        sWT[2 * 64 * 68 + (j4 + 0) * 68 + i] = wv.x; sWT[2 * 64 * 68 + (j4 + 1) * 68 + i] = wv.y;
        sWT[2 * 64 * 68 + (j4 + 2) * 68 + i] = wv.z; sWT[2 * 64 * 68 + (j4 + 3) * 68 + i] = wv.w;
    }
    for (int t = tid; t < 512; t += 256) {
        int i4 = (t & 15) * 4, c = t >> 4;
        *(float4*)&sx[c * 68 + i4] =
            *(const float4*)&x[((size_t)((bh >> 3) * C_ + c0 + c)) * HD_ + h * 64 + i4];
    }
    __syncthreads();
    int j = tid & 63, cg = tid >> 6;     // cg uniform per wave
    float aq[8] = {}, ak[8] = {}, av[8] = {};
    const float* pw0 = &sWT[j * 68];
    const float* pw1 = &sWT[64 * 68 + j * 68];
    const float* pw2 = &sWT[2 * 64 * 68 + j * 68];
    const float* px  = &sx[cg * 8 * 68];
    #pragma unroll 2
    for (int i0 = 0; i0 < 64; i0 += 4) {
        float4 w0 = *(const float4*)(pw0 + i0);
        float4 w1 = *(const float4*)(pw1 + i0);
        float4 w2 = *(const float4*)(pw2 + i0);
        #pragma unroll
        for (int cc = 0; cc < 8; ++cc) {
            float4 xv = *(const float4*)(px + cc * 68 + i0);
            aq[cc] += xv.x * w0.x + xv.y * w0.y + xv.z * w0.z + xv.w * w0.w;
            ak[cc] += xv.x * w1.x + xv.y * w1.y + xv.z * w1.z + xv.w * w1.w;
            av[cc] += xv.x * w2.x + xv.y * w2.y + xv.z * w2.z + xv.w * w2.w;
        }
    }
    float th = theta[h * 64 + j];
    #pragma unroll
    for (int cc = 0; cc < 8; ++cc) {
        int c = c0 + cg * 8 + cc;
        float sn, cs;
        sincosf((float)c * th, &sn, &cs);
        float qr = aq[cc] * cs, qi = aq[cc] * sn;
        float kr = ak[cc] * cs, nki = ak[cc] * sn;   // nki = -Ki
        size_t rq = ((size_t)bh * C_ + c) * 128;
        us h0;
        h0 = f2bf(qr);  Qch[rq + j]      = h0; Qcl[rq + j]      = f2bf(qr  - bf2f(h0));
        h0 = f2bf(qi);  Qch[rq + 64 + j] = h0; Qcl[rq + 64 + j] = f2bf(qi  - bf2f(h0));
        h0 = f2bf(kr);  K1h[rq + j]      = h0; K1l[rq + j]      = f2bf(kr  - bf2f(h0));
        h0 = f2bf(nki); K1h[rq + 64 + j] = h0; K1l[rq + 64 + j] = f2bf(nki - bf2f(h0));
    }
    __syncthreads();
    float* T0 = smem;                   // [64][33]
    #pragma unroll
    for (int cc = 0; cc < 8; ++cc)
        T0[j * 33 + cg * 8 + cc] = av[cc];
    __syncthreads();
    int cc2 = tid & 31, jg = tid >> 5;
    #pragma unroll
    for (int jj = 0; jj < 8; ++jj) {
        int jr = jg * 8 + jj;
        float v = T0[jr * 33 + cc2];
        us hh = f2bf(v);
        size_t o = ((size_t)bh * 64 + jr) * C_ + c0 + cc2;
        VTh[o] = hh;
        VTl[o] = f2bf(v - bf2f(hh));
    }
}

// ---------------- MFMA Retention (R17 VERBATIM — proven 98.5us) -----------
// R17: in-reg S (swapped QK, R16-verified) + cooperative K stage. 98.5us,
// MfmaUtil 34.5%. R18's prefetch-across-barrier SPILLED (WRITE +194MB
// scratch, 139us) — twice-falsified (R16, R18); do not reintroduce.
__global__ __launch_bounds__(256, 3) void retention_kernel(
    const us* __restrict__ Qch, const us* __restrict__ Qcl,
    const us* __restrict__ K1h, const us* __restrict__ K1l,
    const us* __restrict__ VTh, const us* __restrict__ VTl,
    float* __restrict__ Pbuf,
    const float* __restrict__ gamma, const float* __restrict__ qk_scale)
{
    constexpr int SPV = 68;            // V row pad (shorts)
    constexpr int SPK = 132;           // K row pad (shorts), 8B-aligned rows
    constexpr int PLV = 64 * SPV;      // 4352 shorts
    constexpr int PLK = 64 * SPK;      // 8448 shorts
    __shared__ us smem[2 * PLK + 2 * PLV];   // 51,200 B
    us* sKh = smem;
    us* sKl = smem + PLK;
    us* sVh = smem + 2 * PLK;
    us* sVl = smem + 2 * PLK + PLV;

    const int tid = threadIdx.x;
    const int w = tid >> 6, lane = tid & 63;
    const int ln = lane & 15, quad = lane >> 4;
    const int r = (int)blockIdx.x >> 4, bh = (int)blockIdx.x & 15;
    const int h = bh & 7;
    int qt, klo, slot;
    if (r == 0)       { qt = 15; klo = 0;  slot = 15; }
    else if (r == 1)  { qt = 31; klo = 16; slot = 47; }
    else if (r <= 17) { qt = 14 + r; klo = 0; slot = 16 + 2 * (qt - 16); }
    else {
        int u = r - 18, s = 15 - (u >> 1);
        if ((u & 1) == 0) { qt = s - 1;  klo = 0;  slot = qt; }
        else              { qt = 15 + s; klo = 16; slot = 17 + 2 * (qt - 16); }
    }
    const int khi = (qt >= 16 && klo == 0) ? 15 : qt;
    const int qc0 = qt * 64;
    const float lg = log2f(gamma[h]);
    const float inv_scale = 1.0f / qk_scale[0];
    const int qloc = w * 16 + ln;                    // this lane's q (tile-local)
    const float rowl = exp2f(lg * (float)qloc);
    const float e16  = exp2f(-16.0f * lg);
    float colq[4];
    #pragma unroll
    for (int r2 = 0; r2 < 4; ++r2)
        colq[r2] = exp2f(-lg * (float)(quad * 4 + r2));

    short8 Qh[4], Ql[4];
    {
        size_t qrow = ((size_t)bh * C_ + qc0 + w * 16 + ln) * 128;
        #pragma unroll
        for (int ck = 0; ck < 4; ++ck) {
            size_t off = qrow + ck * 32 + quad * 8;
            Qh[ck] = *(const short8*)(Qch + off);
            Ql[ck] = *(const short8*)(Qcl + off);
        }
    }
    f32x4 zz = {0.0f, 0.0f, 0.0f, 0.0f};
    f32x4 Or[4], Oi[4];
    #pragma unroll
    for (int it = 0; it < 4; ++it) { Or[it] = zz; Oi[it] = zz; }

    const size_t vtb = (size_t)bh * 64 * C_;
    const int krow_s = tid >> 2, kseg = (tid & 3) * 32;   // K stage coords
    const int vi = tid >> 2, vseg = (tid & 3) * 16;       // V stage coords

    for (int kt = klo; kt <= khi; ++kt) {
        const int kc0 = kt * 64;
        __syncthreads();   // all waves done reading sK/sV of kt-1
        {   // ---- cooperative stage: K (once per block!) + V, all loads together
            const size_t kb = ((size_t)bh * C_ + kc0 + krow_s) * 128 + kseg;
            const us* gh = K1h + kb;
            const us* gl = K1l + kb;
            us* dkh = &sKh[krow_s * SPK + kseg];
            us* dkl = &sKl[krow_s * SPK + kseg];
            #pragma unroll
            for (int m = 0; m < 4; ++m) {
                short8 a = *(const short8*)(gh + m * 8);
                *(short4v*)(dkh + m * 8)     = __builtin_shufflevector(a, a, 0, 1, 2, 3);
                *(short4v*)(dkh + m * 8 + 4) = __builtin_shufflevector(a, a, 4, 5, 6, 7);
                a = *(const short8*)(gl + m * 8);
                *(short4v*)(dkl + m * 8)     = __builtin_shufflevector(a, a, 0, 1, 2, 3);
                *(short4v*)(dkl + m * 8 + 4) = __builtin_shufflevector(a, a, 4, 5, 6, 7);
            }
            size_t g = vtb + (size_t)vi * C_ + kc0 + vseg;
            short8 a = *(const short8*)(VTh + g);
            short8 bq = *(const short8*)(VTh + g + 8);
            *(short4v*)&sVh[vi * SPV + vseg]      = __builtin_shufflevector(a, a, 0, 1, 2, 3);
            *(short4v*)&sVh[vi * SPV + vseg + 4]  = __builtin_shufflevector(a, a, 4, 5, 6, 7);
            *(short4v*)&sVh[vi * SPV + vseg + 8]  = __builtin_shufflevector(bq, bq, 0, 1, 2, 3);
            *(short4v*)&sVh[vi * SPV + vseg + 12] = __builtin_shufflevector(bq, bq, 4, 5, 6, 7);
            a  = *(const short8*)(VTl + g);
            bq = *(const short8*)(VTl + g + 8);
            *(short4v*)&sVl[vi * SPV + vseg]      = __builtin_shufflevector(a, a, 0, 1, 2, 3);
            *(short4v*)&sVl[vi * SPV + vseg + 4]  = __builtin_shufflevector(a, a, 4, 5, 6, 7);
            *(short4v*)&sVl[vi * SPV + vseg + 8]  = __builtin_shufflevector(bq, bq, 0, 1, 2, 3);
            *(short4v*)&sVl[vi * SPV + vseg + 12] = __builtin_shufflevector(bq, bq, 4, 5, 6, 7);
        }
        __syncthreads();   // staged tile ready; no further barrier this kt
        const float tf = exp2f(lg * (float)(qc0 - kc0)) * inv_scale;
        const bool diag = (kt == qt);
        float snt = tf * rowl;
        #pragma unroll
        for (int half = 0; half < 2; ++half) {
            unsigned WRH[2][2], WRL[2][2], WIH[2][2], WIL[2][2];
            #pragma unroll
            for (int n2 = 0; n2 < 2; ++n2) {
                const int nt = half * 2 + n2;
                const int kr = (nt * 16 + ln) * SPK;
                short8 Kh[4], Kl[4];
                #pragma unroll
                for (int ck = 0; ck < 4; ++ck) {
                    Kh[ck] = lds_frag(&sKh[kr + ck * 32 + quad * 8]);
                    Kl[ck] = lds_frag(&sKl[kr + ck * 32 + quad * 8]);
                }
                // swapped QK (R16-verified): S^T = K·Q
                f32x4 sr = zz, si = zz;
                #pragma unroll
                for (int ck = 0; ck < 4; ++ck) {
                    sr = mfma16(Kh[ck], Qh[ck], sr);
                    sr = mfma16(Kl[ck], Qh[ck], sr);
                    sr = mfma16(Kh[ck], Ql[ck], sr);
                }
                short8 nKh2 = negbf(Kh[2]), nKh3 = negbf(Kh[3]);
                short8 nKl2 = negbf(Kl[2]), nKl3 = negbf(Kl[3]);
                si = mfma16(nKh2, Qh[0], si); si = mfma16(nKl2, Qh[0], si); si = mfma16(nKh2, Ql[0], si);
                si = mfma16(nKh3, Qh[1], si); si = mfma16(nKl3, Qh[1], si); si = mfma16(nKh3, Ql[1], si);
                si = mfma16(Kh[0], Qh[2], si); si = mfma16(Kl[0], Qh[2], si); si = mfma16(Kh[0], Ql[2], si);
                si = mfma16(Kh[1], Qh[3], si); si = mfma16(Kl[1], Qh[3], si); si = mfma16(Kh[1], Ql[3], si);
                // decay weight + causal mask in transposed layout (R16-verified):
                // lane holds S[qloc][k = nt*16 + quad*4 + r2]
                float ar[4], ai[4];
                #pragma unroll
                for (int r2 = 0; r2 < 4; ++r2) {
                    float wv = snt * colq[r2];
                    if (diag && (qloc < nt * 16 + quad * 4 + r2)) wv = 0.0f;
                    ar[r2] = sr[r2] * wv;
                    ai[r2] = si[r2] * wv;
                }
                pkhl(ar[0], ar[1], WRH[n2][0], WRL[n2][0]);
                pkhl(ar[2], ar[3], WRH[n2][1], WRL[n2][1]);
                pkhl(ai[0], ai[1], WIH[n2][0], WIL[n2][0]);
                pkhl(ai[2], ai[3], WIH[n2][1], WIL[n2][1]);
                snt *= e16;
            }
            // PV A-frags in-register; V read permuted to match (R16-verified)
            short8 SRH = bcs8(WRH[0][0], WRH[0][1], WRH[1][0], WRH[1][1]);
            short8 SRL = bcs8(WRL[0][0], WRL[0][1], WRL[1][0], WRL[1][1]);
            short8 SIH = bcs8(WIH[0][0], WIH[0][1], WIH[1][0], WIH[1][1]);
            short8 SIL = bcs8(WIL[0][0], WIL[0][1], WIL[1][0], WIL[1][1]);
            #pragma unroll
            for (int it = 0; it < 4; ++it) {
                int vb = (it * 16 + ln) * SPV + half * 32 + quad * 4;
                short8 Vh = lds_fragg(&sVh[vb]);
                short8 Vl = lds_fragg(&sVl[vb]);
                Or[it] = mfma16(SRH, Vh, Or[it]);
                Or[it] = mfma16(SRH, Vl, Or[it]);
                Or[it] = mfma16(SRL, Vh, Or[it]);
                Oi[it] = mfma16(SIH, Vh, Oi[it]);
                Oi[it] = mfma16(SIH, Vl, Oi[it]);
                Oi[it] = mfma16(SIL, Vh, Oi[it]);
            }
        }
    }
    float* Pr = Pbuf + ((size_t)(bh * 48 + slot)) * 8192;
    float* Pi = Pr + 4096;
    #pragma unroll
    for (int it = 0; it < 4; ++it) {
        #pragma unroll
        for (int rr2 = 0; rr2 < 4; ++rr2) {
            int qL = w * 16 + quad * 4 + rr2, iX = it * 16 + ln;
            Pr[qL * 64 + iX] = Or[it][rr2];
            Pi[qL * 64 + iX] = Oi[it][rr2];
        }
    }
}

// -------- Merged: partial reduce + L2 norm -> A1   AND   weight cvt --------
// grid (64, 16): bx<32 -> reduce (qt=bx, bh=by); bx>=32 -> wcvt tile.
__global__ __launch_bounds__(256) void reduce_wcvt_kernel(
    const float* __restrict__ Pbuf,
    us* __restrict__ A1h, us* __restrict__ A1l,
    const float* __restrict__ WG, const float* __restrict__ WO,
    us* __restrict__ Gh, us* __restrict__ Gl,
    us* __restrict__ Oh, us* __restrict__ Ol)
{
    __shared__ float T[32 * 33];
    if ((int)blockIdx.x < 32) {
        const int qt = blockIdx.x, bh = blockIdx.y;
        const int h = bh & 7, b = bh >> 3;
        const int t = threadIdx.x;
        const int q = t >> 2, i0 = (t & 3) * 16;
        const int slot0 = (qt < 16) ? qt : 16 + 2 * (qt - 16);
        const int nparts = (qt < 16) ? 1 : 2;
        const float* P0 = Pbuf + ((size_t)(bh * 48 + slot0)) * 8192 + q * 64 + i0;
        float orv[16], oiv[16];
        #pragma unroll
        for (int s4 = 0; s4 < 4; ++s4) {
            *(float4*)&orv[s4 * 4] = *(const float4*)(P0 + s4 * 4);
            *(float4*)&oiv[s4 * 4] = *(const float4*)(P0 + 4096 + s4 * 4);
        }
        if (nparts == 2) {
            const float* P1 = P0 + 8192;
            #pragma unroll
            for (int s4 = 0; s4 < 4; ++s4) {
                float4 a = *(const float4*)(P1 + s4 * 4);
                float4 c = *(const float4*)(P1 + 4096 + s4 * 4);
                orv[s4 * 4]     += a.x; orv[s4 * 4 + 1] += a.y;
                orv[s4 * 4 + 2] += a.z; orv[s4 * 4 + 3] += a.w;
                oiv[s4 * 4]     += c.x; oiv[s4 * 4 + 1] += c.y;
                oiv[s4 * 4 + 2] += c.z; oiv[s4 * 4 + 3] += c.w;
            }
        }
        float ss = 0.0f;
        #pragma unroll
        for (int k = 0; k < 16; ++k) ss += orv[k] * orv[k] + oiv[k] * oiv[k];
        ss += __shfl_xor(ss, 1);
        ss += __shfl_xor(ss, 2);
        float rn = rsqrtf(ss);
        size_t o = (((size_t)(b * C_ + qt * 64 + q)) * H_ + h) * HW_ + i0;
        us th[16], tl[16];
        #pragma unroll
        for (int k = 0; k < 16; ++k) {
            float v = orv[k] * rn;
            us hh = f2bf(v); th[k] = hh; tl[k] = f2bf(v - bf2f(hh));
        }
        *(short8*)&A1h[o] = *(short8*)&th[0]; *(short8*)&A1h[o + 8] = *(short8*)&th[8];
        *(short8*)&A1l[o] = *(short8*)&tl[0]; *(short8*)&A1l[o + 8] = *(short8*)&tl[8];
        #pragma unroll
        for (int k = 0; k < 16; ++k) {
            float v = oiv[k] * rn;
            us hh = f2bf(v); th[k] = hh; tl[k] = f2bf(v - bf2f(hh));
        }
        *(short8*)&A1h[N1_ + o] = *(short8*)&th[0]; *(short8*)&A1h[N1_ + o + 8] = *(short8*)&th[8];
        *(short8*)&A1l[N1_ + o] = *(short8*)&tl[0]; *(short8*)&A1l[N1_ + o + 8] = *(short8*)&tl[8];
    } else {
        int widx = ((int)blockIdx.x - 32) * 16 + (int)blockIdx.y;  // 0..511
        int z = widx >> 8, w2 = widx & 255;
        const float* src = z ? WO : WG;
        us* dh = z ? Oh : Gh;
        us* dl = z ? Ol : Gl;
        int k0 = (w2 >> 4) * 32, n0 = (w2 & 15) * 32;
        int c = threadIdx.x & 31, r8 = threadIdx.x >> 5;
        #pragma unroll
        for (int rr = 0; rr < 4; ++rr) {
            int rw = r8 * 4 + rr;
            T[rw * 33 + c] = src[(size_t)(k0 + rw) * 512 + n0 + c];
        }
        __syncthreads();
        #pragma unroll
        for (int rr = 0; rr < 4; ++rr) {
            int rw = r8 * 4 + rr;           // n-local
            float v = T[c * 33 + rw];       // [k-local=c][n-local=rw]
            us hh = f2bf(v);
            size_t o = (size_t)(n0 + rw) * 512 + k0 + c;
            dh[o] = hh; dl[o] = f2bf(v - bf2f(hh));
        }
    }
}

// ------- Fused G-GEMM + complex gate: A2 = gate(A1, A1*WG) -----------------
// R21: R20's cooperative B staging + M-tile 64 (grid 64x8 = 512 blocks =
// 2 blocks/CU, 8 waves/SIMD-group). R19's tile-halving regressed WITHOUT
// staging (B per-wave redundancy x2); with staging B is fetched once per
// block from the L2-resident 1MB panel, so the extra blocks are cheap and
// buy the TLP these latency-bound kernels lacked (was 1 block/CU!).
// Epilogue: __expf/__sincosf — args are tiny (|G|<<1), HW-accurate here.
__global__ __launch_bounds__(256) void gemm_gate_kernel(
    const us* __restrict__ Ah, const us* __restrict__ Al,
    const us* __restrict__ BTh, const us* __restrict__ BTl,
    us* __restrict__ A2h, us* __restrict__ A2l)
{
    constexpr int SPB = 132;            // B row pad (shorts)
    constexpr int PLB = 64 * SPB;       // 8448 shorts
    __shared__ us sB[2 * PLB];          // 33,792 B
    us* sBh = sB;
    us* sBl = sB + PLB;
    const int tid = threadIdx.x;
    const int w = tid >> 6, lane = tid & 63;
    const int ln = lane & 15, quad = lane >> 4;
    const int bm = blockIdx.x * 64 + w * 16;   // re-plane rows [0,4096)
    const int bn = blockIdx.y * 64;
    const int brow = tid >> 2, bseg = (tid & 3) * 32;  // B stage coords
    f32x4 accR[4], accI[4];
    #pragma unroll
    for (int nt = 0; nt < 4; ++nt) {
        accR[nt] = (f32x4){0.f, 0.f, 0.f, 0.f};
        accI[nt] = (f32x4){0.f, 0.f, 0.f, 0.f};
    }
    const us* pAr[2];
    const us* pAi[2];
    {
        size_t rr = (size_t)(bm + ln) * 512 + quad * 8;
        pAr[0] = Ah + rr;        pAr[1] = Al + rr;
        pAi[0] = Ah + N1_ + rr;  pAi[1] = Al + N1_ + rr;
    }
    for (int kc = 0; kc < 4; ++kc) {
        const int kc0 = kc * 128;
        __syncthreads();
        {   // cooperative B stage: row brow, shorts [bseg, bseg+32) of chunk
            const size_t gb = (size_t)(bn + brow) * 512 + kc0 + bseg;
            us* dh = &sBh[brow * SPB + bseg];
            us* dl = &sBl[brow * SPB + bseg];
            #pragma unroll
            for (int m = 0; m < 4; ++m) {
                short8 a = *(const short8*)(BTh + gb + m * 8);
                *(short4v*)(dh + m * 8)     = __builtin_shufflevector(a, a, 0, 1, 2, 3);
                *(short4v*)(dh + m * 8 + 4) = __builtin_shufflevector(a, a, 4, 5, 6, 7);
                a = *(const short8*)(BTl + gb + m * 8);
                *(short4v*)(dl + m * 8)     = __builtin_shufflevector(a, a, 0, 1, 2, 3);
                *(short4v*)(dl + m * 8 + 4) = __builtin_shufflevector(a, a, 4, 5, 6, 7);
            }
        }
        __syncthreads();
        #pragma unroll
        for (int ks = 0; ks < 4; ++ks) {
            const int ko = kc0 + ks * 32;
            const int lo = ks * 32 + quad * 8;
            short8 Ar[2], Ai[2], Bf[4][2];
            Ar[0] = *(const short8*)(pAr[0] + ko);
            Ar[1] = *(const short8*)(pAr[1] + ko);
            Ai[0] = *(const short8*)(pAi[0] + ko);
            Ai[1] = *(const short8*)(pAi[1] + ko);
            #pragma unroll
            for (int nt = 0; nt < 4; ++nt) {
                Bf[nt][0] = lds_frag(&sBh[(nt * 16 + ln) * SPB + lo]);
                Bf[nt][1] = lds_frag(&sBl[(nt * 16 + ln) * SPB + lo]);
            }
            #pragma unroll
            for (int nt = 0; nt < 4; ++nt) {
                accR[nt] = mfma16(Ar[0], Bf[nt][0], accR[nt]);
                accR[nt] = mfma16(Ar[0], Bf[nt][1], accR[nt]);
                accR[nt] = mfma16(Ar[1], Bf[nt][0], accR[nt]);
                accI[nt] = mfma16(Ai[0], Bf[nt][0], accI[nt]);
                accI[nt] = mfma16(Ai[0], Bf[nt][1], accI[nt]);
                accI[nt] = mfma16(Ai[1], Bf[nt][0], accI[nt]);
            }
        }
    }
    // epilogue: gate in-register, write A2 bf16 h/l
    #pragma unroll
    for (int nt = 0; nt < 4; ++nt)
        #pragma unroll
        for (int r = 0; r < 4; ++r) {
            int m = bm + quad * 4 + r;
            int n = bn + nt * 16 + ln;
            size_t idx = (size_t)m * 512 + n;
            float gr = accR[nt][r], gi = accI[nt][r];
            float hr = bf2f(Ah[idx]) + bf2f(Al[idx]);
            float hi = bf2f(Ah[N1_ + idx]) + bf2f(Al[N1_ + idx]);
            float e = __expf(-2.0f * gr);
            float sn, cs;
            __sincosf(2.0f * gi, &sn, &cs);
            float dr = 1.0f + e * cs;
            float di = -e * sn;
            float nr = hr * gr - hi * gi;
            float ni = hr * gi + hi * gr;
            float inv = 1.0f / (dr * dr + di * di);
            float o2r = (nr * dr + ni * di) * inv;
            float o2i = (ni * dr - nr * di) * inv;
            us t = f2bf(o2r);
            A2h[idx] = t; A2l[idx] = f2bf(o2r - bf2f(t));
            t = f2bf(o2i);
            A2h[N1_ + idx] = t; A2l[N1_ + idx] = f2bf(o2i - bf2f(t));
        }
}

// ---------------- split-bf16 MFMA GEMM: C[8192,512] = A * W (WT given) -----
// R21: cooperative B staging + M-tile 64 (grid 128x8 = 1024 blocks = 4/CU).
__global__ __launch_bounds__(256) void gemm_mfma_kernel(
    const us* __restrict__ Ah, const us* __restrict__ Al,
    const us* __restrict__ BTh, const us* __restrict__ BTl,
    float* __restrict__ Cout, int mode)
{
    constexpr int SPB = 132;
    constexpr int PLB = 64 * SPB;
    __shared__ us sB[2 * PLB];          // 33,792 B
    us* sBh = sB;
    us* sBl = sB + PLB;
    const int tid = threadIdx.x;
    const int w = tid >> 6, lane = tid & 63;
    const int ln = lane & 15, quad = lane >> 4;
    const int bm = blockIdx.x * 64 + w * 16;
    const int bn = blockIdx.y * 64;
    const int brow = tid >> 2, bseg = (tid & 3) * 32;
    f32x4 acc[4];
    #pragma unroll
    for (int nt = 0; nt < 4; ++nt) acc[nt] = (f32x4){0.f, 0.f, 0.f, 0.f};
    const us* pA[2];
    {
        size_t r = (size_t)(bm + ln) * 512 + quad * 8;
        pA[0] = Ah + r; pA[1] = Al + r;
    }
    for (int kc = 0; kc < 4; ++kc) {
        const int kc0 = kc * 128;
        __syncthreads();
        {
            const size_t gb = (size_t)(bn + brow) * 512 + kc0 + bseg;
            us* dh = &sBh[brow * SPB + bseg];
            us* dl = &sBl[brow * SPB + bseg];
            #pragma unroll
            for (int m = 0; m < 4; ++m) {
                short8 a = *(const short8*)(BTh + gb + m * 8);
                *(short4v*)(dh + m * 8)     = __builtin_shufflevector(a, a, 0, 1, 2, 3);
                *(short4v*)(dh + m * 8 + 4) = __builtin_shufflevector(a, a, 4, 5, 6, 7);
                a = *(const short8*)(BTl + gb + m * 8);
                *(short4v*)(dl + m * 8)     = __builtin_shufflevector(a, a, 0, 1, 2, 3);
                *(short4v*)(dl + m * 8 + 4) = __builtin_shufflevector(a, a, 4, 5, 6, 7);
            }
        }
        __syncthreads();
        #pragma unroll
        for (int ks = 0; ks < 4; ++ks) {
            const int ko = kc0 + ks * 32;
            const int lo = ks * 32 + quad * 8;
            short8 Af[2], Bf[4][2];
            Af[0] = *(const short8*)(pA[0] + ko);
            Af[1] = *(const short8*)(pA[1] + ko);
            #pragma unroll
            for (int nt = 0; nt < 4; ++nt) {
                Bf[nt][0] = lds_frag(&sBh[(nt * 16 + ln) * SPB + lo]);
                Bf[nt][1] = lds_frag(&sBl[(nt * 16 + ln) * SPB + lo]);
            }
            #pragma unroll
            for (int nt = 0; nt < 4; ++nt) {
                acc[nt] = mfma16(Af[0], Bf[nt][0], acc[nt]);
                acc[nt] = mfma16(Af[0], Bf[nt][1], acc[nt]);
                acc[nt] = mfma16(Af[1], Bf[nt][0], acc[nt]);
            }
        }
    }
    #pragma unroll
    for (int nt = 0; nt < 4; ++nt)
        #pragma unroll
        for (int r = 0; r < 4; ++r) {
            int m = bm + quad * 4 + r;
            int n = bn + nt * 16 + ln;
            float v = acc[nt][r];
            if (mode == 0) {
                Cout[(size_t)m * 512 + n] = v;
            } else if (mode == 1) {
                if (m < 4096) Cout[2 * ((size_t)m * 512 + n)] = v;
                else          Cout[2 * ((size_t)(m - 4096) * 512 + n) + 1] = v;
            } else {
                if (m < 4096) Cout[(size_t)m * 512 + n] = v;
            }
        }
}

extern "C" void kernel_launch(void* const* d_in, const int* in_sizes, int n_in,
                              void* d_out, int out_size, void* d_ws, size_t ws_size,
                              hipStream_t stream)
{
    const float* x     = (const float*)d_in[0];
    const float* WQ    = (const float*)d_in[1];
    const float* WK    = (const float*)d_in[2];
    const float* WV    = (const float*)d_in[3];
    const float* theta = (const float*)d_in[4];
    const float* gamma = (const float*)d_in[5];
    const float* qk    = (const float*)d_in[7];
    const float* WO    = (const float*)d_in[8];
    const float* WG    = (const float*)d_in[9];
    float* out = (float*)d_out;

    const size_t N1 = (size_t)B_ * H_ * C_ * HW_;       // 2,097,152
    const size_t SQ = (size_t)B_ * H_ * C_ * 128;       // 4,194,304 shorts
    const size_t SV = (size_t)B_ * H_ * HW_ * C_;       // 2,097,152 shorts
    us* usw = (us*)d_ws;
    us *Qch = usw,            *Qcl = usw + SQ,
       *K1h = usw + 2 * SQ,   *K1l = usw + 3 * SQ,
       *VTh = usw + 4 * SQ,   *VTl = usw + 4 * SQ + SV; // shorts end at 5*N1 floats
    float* fw = (float*)d_ws;
    us *A1h = (us*)(fw + 5 * N1), *A1l = (us*)(fw + 6 * N1);
    // WT overlays dead K1 (wcvt blocks run after retention):
    us *WTGh = K1h,            *WTGl = K1h + 262144,
       *WTOh = K1h + 524288,  *WTOl = K1h + 786432;
    us *A2h = (us*)(fw + 9 * N1), *A2l = (us*)(fw + 10 * N1);
    // Pbuf = 3*N1 floats (768 x 8192) spans [7N1,10N1): dead before
    // gemm_gate writes A2 (9N1..11N1) — reduce consumed it already.
    float *Pbuf = fw + 7 * N1;

    proj_kernel<<<dim3(C_ / 32, B_ * H_), 256, 0, stream>>>(
        x, WQ, WK, WV, theta, Qch, Qcl, K1h, K1l, VTh, VTl);
    retention_kernel<<<dim3(768), 256, 0, stream>>>(
        Qch, Qcl, K1h, K1l, VTh, VTl, Pbuf, gamma, qk);
    reduce_wcvt_kernel<<<dim3(64, 16), 256, 0, stream>>>(
        Pbuf, A1h, A1l, WG, WO, WTGh, WTGl, WTOh, WTOl);

    gemm_gate_kernel<<<dim3(64, 8), 256, 0, stream>>>(
        A1h, A1l, WTGh, WTGl, A2h, A2l);

    int outmode = (out_size >= (int)(2 * N1)) ? 1 : 2;
    gemm_mfma_kernel<<<dim3(128, 8), 256, 0, stream>>>(
        A2h, A2l, WTOh, WTOl, out, outmode);
}